// Round 7
// baseline (274.195 us; speedup 1.0000x reference)
//
#include <hip/hip_runtime.h>
#include <math.h>

#define B 8
#define C 256
#define L 2046
#define LP 2048
#define IC 64
#define OC 128
#define BN_EPS 1e-5f
#define INVN (1.f / 16384.f)   // 1/(B*LP)

// ws offsets (float units)
#define OFF_Y1T    0u          // conv1 out (pre-BN) bf16 [b][l][64]
#define OFF_Y2C    524288u     // conv1 out (pre-BN) bf16 [b][64][l]
#define OFF_SAFT   1048576u    // sa_feat bf16 [b][l][64]
#define OFF_SCFT   1572864u    // sc_feat bf16 [b][l][64]
#define OFF_Y51T   2097152u    // conv3 out (pre-BN) bf16 [b][l][64]
#define OFF_Y52T   2621440u
#define OFF_VB     3145728u    // v bf16 [b][64][l]
#define OFF_QT     3670016u    // q bf16 [b][l][8]
#define OFF_KT     3735552u
#define OFF_LPART  3801088u    // pam denominators [b][32][4][64]
#define OFF_EPART  3866624u    // CAM gram partials [b][16][64][64]
#define OFF_ATTN   4390912u
#define OFF_STATS1 4423680u    // [4 copies][128ch][2] atomic sum/sumsq
#define OFF_STATS2 4424704u
#define OFF_W5BF   4425728u    // bf16 [128][256]
#define OFF_W67    4442112u    // bf16 [2][128][64]
#define OFF_WT     4450304u    // bf16 [2][3][64][64]
#define OFF_WQKV   4462592u    // bf16 [80][64]
#define OFF_BQKV   4465152u    // fp32 [80]

typedef __attribute__((ext_vector_type(8))) short bshort8;
typedef __attribute__((ext_vector_type(4))) float f32x4;

// fast bf16 round-half-up (differs from RTNE only on exact ties)
__device__ __forceinline__ unsigned short f2bf(float f) {
    union { float f; unsigned int u; } v; v.f = f;
    return (unsigned short)((v.u + 0x8000u) >> 16);
}
__device__ __forceinline__ float bf2f(unsigned short u) {
    union { unsigned int i; float f; } v; v.i = ((unsigned int)u) << 16;
    return v.f;
}
// pack two floats' rounded bf16: low16 from a, high16 from b (3 VALU via v_perm)
__device__ __forceinline__ unsigned int pk2(float a, float b) {
    union { float f; unsigned int u; } va, vb; va.f = a; vb.f = b;
    return __builtin_amdgcn_perm(vb.u + 0x8000u, va.u + 0x8000u, 0x07060302u);
}

// BN affine coefs from 4-copy atomic stats
__device__ __forceinline__ void load_coef(const float* __restrict__ STATS,
        const float* __restrict__ g, const float* __restrict__ beta,
        int base, int cnt, float* cA, float* cB) {
    int t = threadIdx.x;
    if (t < cnt) {
        int ch = base + t;
        float s = STATS[ch * 2] + STATS[256 + ch * 2] + STATS[512 + ch * 2] + STATS[768 + ch * 2];
        float q = STATS[ch * 2 + 1] + STATS[256 + ch * 2 + 1] + STATS[512 + ch * 2 + 1] + STATS[768 + ch * 2 + 1];
        float mu = s * INVN;
        float var = q * INVN - mu * mu;
        float A = g[t] * rsqrtf(var + BN_EPS);
        cA[t] = A;
        cB[t] = beta[t] - mu * A;
    }
}

// ---- weight prep + stats zero + out b8-init ----
__global__ __launch_bounds__(256) void k_wprep(
        const float* __restrict__ W5a, const float* __restrict__ W5c,
        const float* __restrict__ W6, const float* __restrict__ W7,
        const float* __restrict__ W51, const float* __restrict__ W52,
        const float* __restrict__ Wq, const float* __restrict__ Wk,
        const float* __restrict__ Wv, const float* __restrict__ bq,
        const float* __restrict__ bk, const float* __restrict__ bv,
        const float* __restrict__ b8,
        unsigned short* __restrict__ W5BF, unsigned short* __restrict__ W67,
        unsigned short* __restrict__ WT, unsigned short* __restrict__ WQKV,
        float* __restrict__ BQKV, float* __restrict__ STATS1,
        float* __restrict__ STATS2, float* __restrict__ out_sasc) {
    int i = blockIdx.x * 256 + threadIdx.x;
    if (i < 32768) {
        int o = i >> 8, c = i & 255;
        W5BF[i] = f2bf(o < 64 ? W5a[o * 256 + c] : W5c[(o - 64) * 256 + c]);
    } else if (i < 49152) {
        int j = i - 32768; int g = j >> 13; int r = j & 8191;
        W67[j] = f2bf(g ? W7[r] : W6[r]);
    } else if (i < 73728) {
        int j = i - 49152;
        int c = j & 63, o = (j >> 6) & 63, wt = j >> 12; int w = wt / 3, t = wt % 3;
        const float* Ws = w ? W52 : W51;
        WT[j] = f2bf(Ws[(o * 64 + c) * 3 + t]);
    } else if (i < 78848) {
        int j = i - 49152 - 24576; int o = j >> 6, c = j & 63;
        float v = o < 8 ? Wq[o * 64 + c] : (o < 16 ? Wk[(o - 8) * 64 + c] : Wv[(o - 16) * 64 + c]);
        WQKV[j] = f2bf(v);
    } else if (i < 78928) {
        int o = i - 78848;
        BQKV[o] = o < 8 ? bq[o] : (o < 16 ? bk[o - 8] : bv[o - 16]);
    } else if (i < 80976) {
        int j = i - 78928;
        if (j < 1024) STATS1[j] = 0.f; else STATS2[j - 1024] = 0.f;
    } else if (i < 82000) {
        int j = i - 80976;
        out_sasc[j] = b8[j & 127];
    }
}

// ---- conv1x1(x): single x pass, both branches; pre-BN bf16 + atomic stats ----
// grid (128, B), 256 thr. 16 output rows/block. Wave w: ot pair {2w, 2w+1};
// waves 0,1 -> Y1T (ch 0..63), waves 2,3 -> Y2C (ch 0..63 of branch 2).
__global__ __launch_bounds__(256) void k_conv1(const float* __restrict__ x,
        const unsigned short* __restrict__ W5BF,
        unsigned short* __restrict__ Y1T, unsigned short* __restrict__ Y2C,
        float* __restrict__ STATS1) {
    __shared__ unsigned short xt[16][264];   // source tile [l][c] bf16 (+8 pad)
    __shared__ float lds_part[4][64];
    int lt = blockIdx.x, b = blockIdx.y;
    int l0 = lt * 16;
    int t = threadIdx.x;
    {   // stage: thread t = channel; 16 source l values (ls = l0-1+n)
        const float* xs = x + ((size_t)(b * C + t)) * L;
        int ls0 = l0 - 1;
#pragma unroll
        for (int n = 0; n < 16; ++n) {
            int ls = ls0 + n;
            float v = (ls >= 0 && ls < L) ? xs[ls] : 0.f;
            xt[n][t] = f2bf(v);
        }
    }
    __syncthreads();
    int w = t >> 6, lane = t & 63, n = lane & 15, quad = lane >> 4;
    int lp = l0 + n;
    f32x4 acc[2];
    acc[0] = (f32x4){0.f, 0.f, 0.f, 0.f};
    acc[1] = (f32x4){0.f, 0.f, 0.f, 0.f};
#pragma unroll
    for (int ck = 0; ck < 8; ++ck) {
        bshort8 xb = *(const bshort8*)(&xt[n][ck * 32 + quad * 8]);
#pragma unroll
        for (int oi = 0; oi < 2; ++oi) {
            int ot = w * 2 + oi;
            bshort8 wf = *(const bshort8*)(W5BF + (size_t)(ot * 16 + n) * C + ck * 32 + quad * 8);
            acc[oi] = __builtin_amdgcn_mfma_f32_16x16x32_bf16(wf, xb, acc[oi], 0, 0, 0);
        }
    }
    if (w < 2) {
#pragma unroll
        for (int oi = 0; oi < 2; ++oi) {
            int ot = w * 2 + oi;
            uint2 pv;
            pv.x = pk2(acc[oi][0], acc[oi][1]);
            pv.y = pk2(acc[oi][2], acc[oi][3]);
            *(uint2*)(Y1T + ((size_t)(b * LP + lp)) * IC + ot * 16 + quad * 4) = pv;
        }
    } else {
#pragma unroll
        for (int oi = 0; oi < 2; ++oi) {
            int ot = (w - 2) * 2 + oi;
#pragma unroll
            for (int r = 0; r < 4; ++r) {
                int o = ot * 16 + quad * 4 + r;
                Y2C[((size_t)(b * IC + o)) * LP + lp] = f2bf(acc[oi][r]);
            }
        }
    }
    // per-wave stats (32 channels each, over this block's 16 rows)
#pragma unroll
    for (int oi = 0; oi < 2; ++oi)
#pragma unroll
        for (int r = 0; r < 4; ++r) {
            float s = acc[oi][r], q = s * s;
#pragma unroll
            for (int msk = 1; msk < 16; msk <<= 1) {
                s += __shfl_xor(s, msk, 64);
                q += __shfl_xor(q, msk, 64);
            }
            if (n == 0) {
                int ci = oi * 16 + quad * 4 + r;   // 0..31 within wave
                lds_part[w][ci * 2] = s;
                lds_part[w][ci * 2 + 1] = q;
            }
        }
    __syncthreads();
    {   // ch = t>>1 (0..127); wave covering it = ch>>5
        int ch = t >> 1, wsrc = ch >> 5;
        int idx = ((ch & 31) << 1) | (t & 1);
        atomicAdd(&STATS1[(blockIdx.x & 3) * 256 + t], lds_part[wsrc][idx]);
    }
}

// ================= fuse1: qkv (256 blocks) | gram (32 blocks) =================
__device__ void role_qkv(char* dynsm, int lt, int b,
        const unsigned short* __restrict__ Y1T, const float* __restrict__ STATS1,
        const float* __restrict__ g5a, const float* __restrict__ b5a,
        const unsigned short* __restrict__ WQKV, const float* __restrict__ BQKV,
        unsigned short* __restrict__ QT, unsigned short* __restrict__ KT,
        unsigned short* __restrict__ VB) {
    float* cA = (float*)dynsm;
    float* cB = cA + 64;
    load_coef(STATS1, g5a, b5a, 0, 64, cA, cB);
    __syncthreads();
    int t = threadIdx.x;
    int w = t >> 6, lane = t & 63, n = lane & 15, quad = lane >> 4;
    int lrow = lt * 64 + w * 16 + n;
    bshort8 fb[2];
#pragma unroll
    for (int kt = 0; kt < 2; ++kt) {
        bshort8 raw = *(const bshort8*)(Y1T + ((size_t)(b * LP + lrow)) * IC + kt * 32 + quad * 8);
        bshort8 f;
#pragma unroll
        for (int j = 0; j < 8; ++j) {
            int c = kt * 32 + quad * 8 + j;
            float v = fmaxf(fmaf(cA[c], bf2f((unsigned short)raw[j]), cB[c]), 0.f);
            ((unsigned short*)&f)[j] = f2bf(v);
        }
        fb[kt] = f;
    }
    f32x4 acc[5];
#pragma unroll
    for (int ot = 0; ot < 5; ++ot) {
        f32x4 a = {0.f, 0.f, 0.f, 0.f};
#pragma unroll
        for (int kt = 0; kt < 2; ++kt) {
            bshort8 wf = *(const bshort8*)(WQKV + (size_t)(ot * 16 + n) * IC + kt * 32 + quad * 8);
            a = __builtin_amdgcn_mfma_f32_16x16x32_bf16(wf, fb[kt], a, 0, 0, 0);
        }
        acc[ot] = a;
    }
#pragma unroll
    for (int ot = 0; ot < 5; ++ot)
#pragma unroll
        for (int r = 0; r < 4; ++r) {
            int o = ot * 16 + quad * 4 + r;
            unsigned short bv16 = f2bf(acc[ot][r] + BQKV[o]);
            if (ot == 0) {
                if (o < 8) QT[((size_t)(b * LP + lrow)) * 8 + o] = bv16;
                else KT[((size_t)(b * LP + lrow)) * 8 + (o - 8)] = bv16;
            } else {
                VB[((size_t)(b * IC + (o - 16))) * LP + lrow] = bv16;
            }
        }
}

__device__ void role_gram(char* dynsm, int blk, int b,
        const unsigned short* __restrict__ Y2C, const float* __restrict__ STATS1,
        const float* __restrict__ g5c, const float* __restrict__ b5c,
        float* __restrict__ EPART) {
    float* cA = (float*)dynsm;
    float* cB = cA + 64;
    load_coef(STATS1, g5c, b5c, 64, 64, cA, cB);
    __syncthreads();
    int t = threadIdx.x;
    int w = t >> 6, lane = t & 63, n = lane & 15, quad = lane >> 4;
    f32x4 acc[4][4];
#pragma unroll
    for (int ti = 0; ti < 4; ++ti)
#pragma unroll
        for (int tj = 0; tj < 4; ++tj) acc[ti][tj] = (f32x4){0.f, 0.f, 0.f, 0.f};
    for (int chunk = 0; chunk < 4; ++chunk) {
        int lb = (blk * 4 + w) * 128 + chunk * 32 + quad * 8;
        bshort8 frag[4];
#pragma unroll
        for (int g = 0; g < 4; ++g) {
            int c = g * 16 + n;
            bshort8 raw = *(const bshort8*)(Y2C + ((size_t)(b * IC + c)) * LP + lb);
            bshort8 f;
            float A = cA[c], Bc = cB[c];
#pragma unroll
            for (int j = 0; j < 8; ++j)
                ((unsigned short*)&f)[j] = f2bf(fmaxf(fmaf(A, bf2f((unsigned short)raw[j]), Bc), 0.f));
            frag[g] = f;
        }
#pragma unroll
        for (int ti = 0; ti < 4; ++ti)
#pragma unroll
            for (int tj = 0; tj < 4; ++tj)
                acc[ti][tj] = __builtin_amdgcn_mfma_f32_16x16x32_bf16(frag[ti], frag[tj], acc[ti][tj], 0, 0, 0);
    }
    float* ep = EPART + ((size_t)(b * 16 + blk * 4 + w)) * 4096;
#pragma unroll
    for (int ti = 0; ti < 4; ++ti)
#pragma unroll
        for (int tj = 0; tj < 4; ++tj)
#pragma unroll
            for (int r = 0; r < 4; ++r)
                ep[(ti * 16 + quad * 4 + r) * 64 + tj * 16 + n] = acc[ti][tj][r];
}

__global__ __launch_bounds__(256) void k_fuse1(
        const unsigned short* __restrict__ Y1T, const unsigned short* __restrict__ Y2C,
        const float* __restrict__ STATS1,
        const float* __restrict__ g5a, const float* __restrict__ b5a,
        const float* __restrict__ g5c, const float* __restrict__ b5c,
        const unsigned short* __restrict__ WQKV, const float* __restrict__ BQKV,
        unsigned short* __restrict__ QT, unsigned short* __restrict__ KT,
        unsigned short* __restrict__ VB, float* __restrict__ EPART) {
    extern __shared__ char dynsm[];
    int idx = blockIdx.x;
    if (idx < 256) role_qkv(dynsm, idx & 31, idx >> 5, Y1T, STATS1, g5a, b5a,
                            WQKV, BQKV, QT, KT, VB);
    else { int g = idx - 256; role_gram(dynsm, g & 3, g >> 2, Y2C, STATS1, g5c, b5c, EPART); }
}

// ================= fuse2: pam (1024 blocks) | cam_softmax (8) =================
__device__ void role_pam(char* dynsm, int qt, int ks, int b,
        const unsigned short* __restrict__ qT, const unsigned short* __restrict__ kT,
        const unsigned short* __restrict__ vb,
        unsigned short* __restrict__ OPART, float* __restrict__ LPART) {
    unsigned short* vs = (unsigned short*)dynsm;      // [64][72]
    unsigned short* ps = vs + 4608;                   // 4 x [16][72]
    float* os = (float*)dynsm;                        // [64][65] aliased after loop
    int l0 = qt * 64;
    int tid = threadIdx.x;
    int wq = tid >> 6, lane = tid & 63, n = lane & 15, quad = lane >> 4;
    bshort8 qa = {};
    if (quad == 0)
        qa = *(const bshort8*)(qT + ((size_t)(b * LP + l0 + wq * 16 + n)) * 8);
    f32x4 acc[4];
#pragma unroll
    for (int s = 0; s < 4; ++s) acc[s] = (f32x4){0.f, 0.f, 0.f, 0.f};
    float li[4] = {0.f, 0.f, 0.f, 0.f};
    unsigned short* pw = ps + wq * 16 * 72;

    for (int it = 0; it < 8; ++it) {
        int m0 = ks * 512 + it * 64;
        __syncthreads();
        {
            int row = tid >> 2, chn = tid & 3;
            const unsigned short* src = vb + ((size_t)(b * IC + row)) * LP + m0 + chn * 16;
            unsigned short* dstl = vs + row * 72 + chn * 16;
            *(bshort8*)dstl = *(const bshort8*)src;
            *(bshort8*)(dstl + 8) = *(const bshort8*)(src + 8);
        }
        bshort8 kb[4];
#pragma unroll
        for (int s = 0; s < 4; ++s) kb[s] = (bshort8){};
        if (quad == 0) {
#pragma unroll
            for (int s = 0; s < 4; ++s)
                kb[s] = *(const bshort8*)(kT + ((size_t)(b * LP + m0 + s * 16 + n)) * 8);
        }
        __syncthreads();
        f32x4 sc[4];
#pragma unroll
        for (int s = 0; s < 4; ++s)
            sc[s] = __builtin_amdgcn_mfma_f32_16x16x32_bf16(qa, kb[s],
                        (f32x4){0.f, 0.f, 0.f, 0.f}, 0, 0, 0);
#pragma unroll
        for (int s = 0; s < 4; ++s)
#pragma unroll
            for (int r = 0; r < 4; ++r) {
                float p = __expf(sc[s][r]);
                li[r] += p;
                pw[(quad * 4 + r) * 72 + s * 16 + n] = f2bf(p);
            }
#pragma unroll
        for (int step = 0; step < 2; ++step) {
            bshort8 pa = *(const bshort8*)(pw + n * 72 + step * 32 + quad * 8);
#pragma unroll
            for (int s = 0; s < 4; ++s) {
                bshort8 vf = *(const bshort8*)(vs + (s * 16 + n) * 72 + step * 32 + quad * 8);
                acc[s] = __builtin_amdgcn_mfma_f32_16x16x32_bf16(pa, vf, acc[s], 0, 0, 0);
            }
        }
    }
    __syncthreads();
#pragma unroll
    for (int s = 0; s < 4; ++s)
#pragma unroll
        for (int r = 0; r < 4; ++r)
            os[(s * 16 + n) * 65 + wq * 16 + quad * 4 + r] = acc[s][r];
    size_t lbase = ((size_t)((b * 32 + qt) * 4 + ks)) * 64;
#pragma unroll
    for (int r = 0; r < 4; ++r) {
        float s_ = li[r];
#pragma unroll
        for (int msk = 1; msk < 16; msk <<= 1) s_ += __shfl_xor(s_, msk, 64);
        if (n == 0) LPART[lbase + wq * 16 + quad * 4 + r] = s_;
    }
    __syncthreads();
    size_t ob = ((size_t)((b * 32 + qt) * 4 + ks)) * 4096;
    int c = tid >> 2, qc = tid & 3;
    unsigned int* od = (unsigned int*)(OPART + ob + c * 64 + qc * 16);
#pragma unroll
    for (int i = 0; i < 8; ++i)
        od[i] = pk2(os[c * 65 + qc * 16 + 2 * i], os[c * 65 + qc * 16 + 2 * i + 1]);
}

__device__ void role_cam_softmax(char* dynsm, int b,
        const float* __restrict__ EPART, float* __restrict__ attn) {
    float* e = (float*)dynsm;
    int t = threadIdx.x;
    for (int idx = t; idx < 4096; idx += 256) {
        float s = 0.f;
        for (int ch = 0; ch < 16; ++ch) s += EPART[((size_t)(b * 16 + ch)) * 4096 + idx];
        e[idx] = s;
    }
    __syncthreads();
    if (t < 64) {
        float mn = INFINITY;
        for (int d = 0; d < 64; ++d) mn = fminf(mn, e[t * 64 + d]);
        float s = 0.f;
        float* a = attn + (size_t)b * 4096 + t * 64;
        for (int d = 0; d < 64; ++d) { float p = __expf(mn - e[t * 64 + d]); a[d] = p; s += p; }
        float inv = 1.f / s;
        for (int d = 0; d < 64; ++d) a[d] *= inv;
    }
}

__global__ __launch_bounds__(256) void k_fuse2(
        const unsigned short* __restrict__ QT, const unsigned short* __restrict__ KT,
        const unsigned short* __restrict__ VB,
        unsigned short* __restrict__ OPART, float* __restrict__ LPART,
        const float* __restrict__ EPART, float* __restrict__ ATTN) {
    extern __shared__ char dynsm[];
    int idx = blockIdx.x;
    if (idx < 1024) role_pam(dynsm, idx & 31, (idx >> 5) & 3, idx >> 7, QT, KT, VB, OPART, LPART);
    else role_cam_softmax(dynsm, idx - 1024, EPART, ATTN);
}

// ============ fuse3: pam_combine (256 blocks) | cam_apply (128) ============
__device__ void role_pam_combine(char* dynsm, int qt, int b,
        const unsigned short* __restrict__ OPART, const float* __restrict__ LPART,
        const unsigned short* __restrict__ Y1T, const float* __restrict__ STATS1,
        const float* __restrict__ g5a, const float* __restrict__ b5a,
        const float* __restrict__ gamma, unsigned short* __restrict__ SAFT) {
    float* dn = (float*)dynsm;
    float* cA = dn + 64;
    float* cB = cA + 64;
    unsigned short* tile = (unsigned short*)(cB + 64);   // 64*66
    int l0 = qt * 64;
    int t = threadIdx.x;
    load_coef(STATS1, g5a, b5a, 0, 64, cA, cB);
    if (t < 64) {
        size_t lbase = ((size_t)((b * 32 + qt) * 4)) * 64;
        dn[t] = LPART[lbase + t] + LPART[lbase + 64 + t] +
                LPART[lbase + 128 + t] + LPART[lbase + 192 + t];
    }
    __syncthreads();
    int c = t >> 2, qc = t & 3;
    float O[16];
#pragma unroll
    for (int i = 0; i < 16; ++i) O[i] = 0.f;
    size_t ob = ((size_t)((b * 32 + qt) * 4)) * 4096 + c * 64 + qc * 16;
#pragma unroll
    for (int s = 0; s < 4; ++s) {
        bshort8 p0 = *(const bshort8*)(OPART + ob + (size_t)s * 4096);
        bshort8 p1 = *(const bshort8*)(OPART + ob + (size_t)s * 4096 + 8);
#pragma unroll
        for (int i = 0; i < 8; ++i) {
            O[i]     += bf2f((unsigned short)p0[i]);
            O[8 + i] += bf2f((unsigned short)p1[i]);
        }
    }
    float gm = gamma[0];
#pragma unroll
    for (int i = 0; i < 16; ++i) {
        int q = qc * 16 + i;
        unsigned short raw = Y1T[((size_t)(b * LP + l0 + q)) * IC + c];
        float f1v = fmaxf(fmaf(cA[c], bf2f(raw), cB[c]), 0.f);
        float val = fmaf(gm, O[i] / dn[q], f1v);
        tile[q * 66 + c] = f2bf(val);
    }
    __syncthreads();
    int li = t >> 2, cc = t & 3;
    unsigned int* dst = (unsigned int*)(SAFT + ((size_t)(b * LP + l0 + li)) * IC + cc * 16);
#pragma unroll
    for (int i = 0; i < 8; ++i)
        dst[i] = *(unsigned int*)(tile + li * 66 + cc * 16 + 2 * i);
}

__device__ void role_cam_apply(char* dynsm, int blkx, int b,
        const float* __restrict__ attn, const unsigned short* __restrict__ Y2C,
        const float* __restrict__ STATS1,
        const float* __restrict__ g5c, const float* __restrict__ b5c,
        const float* __restrict__ gamma, unsigned short* __restrict__ SCFT) {
    float* as = (float*)dynsm;                    // 4096 floats
    float* cA = as + 4096;
    float* cB = cA + 64;
    unsigned short* tile = (unsigned short*)(cB + 64);  // 128*66
    int l0 = blkx * 128;
    int t = threadIdx.x;
    int lq = t & 127, ch = t >> 7;
    load_coef(STATS1, g5c, b5c, 64, 64, cA, cB);
    for (int i = t; i < 4096; i += 256) as[i] = attn[(size_t)b * 4096 + i];
    __syncthreads();
    float acc[32];
#pragma unroll
    for (int i = 0; i < 32; ++i) acc[i] = 0.f;
    const unsigned short* fb = Y2C + (size_t)b * IC * LP + l0 + lq;
    for (int d4 = 0; d4 < 16; ++d4) {
        float fv[4];
#pragma unroll
        for (int i = 0; i < 4; ++i) {
            int d = 4 * d4 + i;
            fv[i] = fmaxf(fmaf(cA[d], bf2f(fb[(size_t)d * LP]), cB[d]), 0.f);
        }
#pragma unroll
        for (int cc = 0; cc < 32; ++cc) {
            const float4 a4 = *reinterpret_cast<const float4*>(as + (ch * 32 + cc) * 64 + d4 * 4);
            acc[cc] += a4.x * fv[0] + a4.y * fv[1] + a4.z * fv[2] + a4.w * fv[3];
        }
    }
    float gm = gamma[0];
#pragma unroll
    for (int cc = 0; cc < 32; ++cc) {
        int c = ch * 32 + cc;
        float res = fmaxf(fmaf(cA[c], bf2f(fb[(size_t)c * LP]), cB[c]), 0.f);
        tile[lq * 66 + c] = f2bf(fmaf(gm, acc[cc], res));
    }
    __syncthreads();
    int li = t >> 1, half = t & 1;
    unsigned int* dst = (unsigned int*)(SCFT + ((size_t)(b * LP + l0 + li)) * IC + half * 32);
#pragma unroll
    for (int i = 0; i < 16; ++i)
        dst[i] = *(unsigned int*)(tile + li * 66 + half * 32 + 2 * i);
}

__global__ __launch_bounds__(256) void k_fuse3(
        const unsigned short* __restrict__ OPART, const float* __restrict__ LPART,
        const unsigned short* __restrict__ Y1T, const unsigned short* __restrict__ Y2C,
        const float* __restrict__ STATS1,
        const float* __restrict__ g5a, const float* __restrict__ b5a,
        const float* __restrict__ g5c, const float* __restrict__ b5c,
        const float* __restrict__ gpam, const float* __restrict__ gcam,
        const float* __restrict__ ATTN,
        unsigned short* __restrict__ SAFT, unsigned short* __restrict__ SCFT) {
    extern __shared__ char dynsm[];
    int idx = blockIdx.x;
    if (idx < 256) role_pam_combine(dynsm, idx & 31, idx >> 5, OPART, LPART, Y1T,
                                    STATS1, g5a, b5a, gpam, SAFT);
    else { int g = idx - 256; role_cam_apply(dynsm, g & 15, g >> 4, ATTN, Y2C,
                                             STATS1, g5c, b5c, gcam, SCFT); }
}

// ---- conv3 (both branches) -> pre-BN bf16 + atomic stats ----
__global__ __launch_bounds__(256) void k_conv3(const unsigned short* __restrict__ SAFT,
        const unsigned short* __restrict__ SCFT, const unsigned short* __restrict__ WTall,
        unsigned short* __restrict__ Y51T, unsigned short* __restrict__ Y52T,
        float* __restrict__ STATS2) {
    __shared__ float lds_part[4][128];
    int lt = blockIdx.x, og = blockIdx.y, b = blockIdx.z;
    const unsigned short* FTsrc = og ? SCFT : SAFT;
    const unsigned short* WT = WTall + og * 12288;
    unsigned short* dst = og ? Y52T : Y51T;
    int l0 = lt * 64;
    int w = threadIdx.x >> 6, lane = threadIdx.x & 63, n = lane & 15, quad = lane >> 4;
    int lrow = l0 + w * 16 + n;
    f32x4 acc[4];
#pragma unroll
    for (int ot = 0; ot < 4; ++ot) acc[ot] = (f32x4){0.f, 0.f, 0.f, 0.f};
#pragma unroll
    for (int t3 = 0; t3 < 3; ++t3) {
        int row = lrow + t3 - 1;
        bshort8 fb[2];
#pragma unroll
        for (int kt = 0; kt < 2; ++kt) {
            if (row >= 0 && row < LP)
                fb[kt] = *(const bshort8*)(FTsrc + ((size_t)(b * LP + row)) * IC + kt * 32 + quad * 8);
            else fb[kt] = (bshort8){};
        }
#pragma unroll
        for (int ot = 0; ot < 4; ++ot)
#pragma unroll
            for (int kt = 0; kt < 2; ++kt) {
                bshort8 wf = *(const bshort8*)(WT + ((size_t)(t3 * 64 + ot * 16 + n)) * IC + kt * 32 + quad * 8);
                acc[ot] = __builtin_amdgcn_mfma_f32_16x16x32_bf16(wf, fb[kt], acc[ot], 0, 0, 0);
            }
    }
#pragma unroll
    for (int ot = 0; ot < 4; ++ot) {
        uint2 pv;
        pv.x = pk2(acc[ot][0], acc[ot][1]);
        pv.y = pk2(acc[ot][2], acc[ot][3]);
        *(uint2*)(dst + ((size_t)(b * LP + lrow)) * IC + ot * 16 + quad * 4) = pv;
    }
#pragma unroll
    for (int ot = 0; ot < 4; ++ot)
#pragma unroll
        for (int r = 0; r < 4; ++r) {
            float s = acc[ot][r], q = s * s;
#pragma unroll
            for (int msk = 1; msk < 16; msk <<= 1) {
                s += __shfl_xor(s, msk, 64);
                q += __shfl_xor(q, msk, 64);
            }
            if (n == 0) {
                int cch = ot * 16 + quad * 4 + r;
                lds_part[w][cch * 2] = s;
                lds_part[w][cch * 2 + 1] = q;
            }
        }
    __syncthreads();
    int t = threadIdx.x;
    if (t < 128) {
        float s = lds_part[0][t] + lds_part[1][t] + lds_part[2][t] + lds_part[3][t];
        atomicAdd(&STATS2[(blockIdx.x & 3) * 256 + og * 128 + t], s);
    }
}

// ---- final conv1x1 pair + fused sasc projection (out pre-initialized to b8) ----
__global__ __launch_bounds__(256) void k_final(const unsigned short* __restrict__ Y51T,
        const unsigned short* __restrict__ Y52T, const float* __restrict__ STATS2,
        const float* __restrict__ g51, const float* __restrict__ b51,
        const float* __restrict__ g52, const float* __restrict__ b52,
        const unsigned short* __restrict__ W67,
        const float* __restrict__ b6, const float* __restrict__ b7,
        const float* __restrict__ W8,
        float* __restrict__ out_sa, float* __restrict__ out_sc,
        float* __restrict__ out_sasc) {
    __shared__ float cA[128], cB[128];
    __shared__ float fsw[4][64];
    __shared__ float chsum[64];
    int lt = blockIdx.x, og = blockIdx.y, b = blockIdx.z;
    int t = threadIdx.x;
    if (t < 128) {
        float s = STATS2[t * 2] + STATS2[256 + t * 2] + STATS2[512 + t * 2] + STATS2[768 + t * 2];
        float q = STATS2[t * 2 + 1] + STATS2[256 + t * 2 + 1] + STATS2[512 + t * 2 + 1] + STATS2[768 + t * 2 + 1];
        float mu = s * INVN, var = q * INVN - mu * mu;
        float gv = t < 64 ? g51[t] : g52[t - 64];
        float bv = t < 64 ? b51[t] : b52[t - 64];
        float A = gv * rsqrtf(var + BN_EPS);
        cA[t] = A; cB[t] = bv - mu * A;
    }
    __syncthreads();
    int w = t >> 6, lane = t & 63, n = lane & 15, quad = lane >> 4;
    int lrow = lt * 64 + w * 16 + n;
    float fs_lane[16];
    bshort8 ba[2], bb[2];
#pragma unroll
    for (int kt = 0; kt < 2; ++kt) {
        bshort8 ra = *(const bshort8*)(Y51T + ((size_t)(b * LP + lrow)) * IC + kt * 32 + quad * 8);
        bshort8 rb = *(const bshort8*)(Y52T + ((size_t)(b * LP + lrow)) * IC + kt * 32 + quad * 8);
        bshort8 fa, fb;
#pragma unroll
        for (int j = 0; j < 8; ++j) {
            int c = kt * 32 + quad * 8 + j;
            float v1 = fmaxf(fmaf(cA[c], bf2f((unsigned short)ra[j]), cB[c]), 0.f);
            float v2 = fmaxf(fmaf(cA[64 + c], bf2f((unsigned short)rb[j]), cB[64 + c]), 0.f);
            ((unsigned short*)&fa)[j] = f2bf(v1);
            ((unsigned short*)&fb)[j] = f2bf(v2);
            fs_lane[kt * 8 + j] = v1 + v2;
        }
        ba[kt] = fa; bb[kt] = fb;
    }
    f32x4 accA[4], accB[4];
#pragma unroll
    for (int ot = 0; ot < 4; ++ot) {
        accA[ot] = (f32x4){0.f, 0.f, 0.f, 0.f};
        accB[ot] = (f32x4){0.f, 0.f, 0.f, 0.f};
    }
#pragma unroll
    for (int ot = 0; ot < 4; ++ot)
#pragma unroll
        for (int kt = 0; kt < 2; ++kt) {
            bshort8 wa = *(const bshort8*)(W67 + (size_t)(og * 64 + ot * 16 + n) * IC + kt * 32 + quad * 8);
            bshort8 wb = *(const bshort8*)(W67 + 8192 + (size_t)(og * 64 + ot * 16 + n) * IC + kt * 32 + quad * 8);
            accA[ot] = __builtin_amdgcn_mfma_f32_16x16x32_bf16(wa, ba[kt], accA[ot], 0, 0, 0);
            accB[ot] = __builtin_amdgcn_mfma_f32_16x16x32_bf16(wb, bb[kt], accB[ot], 0, 0, 0);
        }
#pragma unroll
    for (int ot = 0; ot < 4; ++ot)
#pragma unroll
        for (int r = 0; r < 4; ++r) {
            int o = og * 64 + ot * 16 + quad * 4 + r;
            out_sa[((size_t)(b * OC + o)) * LP + lrow] = accA[ot][r] + b6[o];
            out_sc[((size_t)(b * OC + o)) * LP + lrow] = accB[ot][r] + b7[o];
        }
    if (og == 0) {
#pragma unroll
        for (int i = 0; i < 16; ++i) {
            float s = fs_lane[i];
#pragma unroll
            for (int msk = 1; msk < 16; msk <<= 1) s += __shfl_xor(s, msk, 64);
            if (n == 0) {
                int c = (i >> 3) * 32 + quad * 8 + (i & 7);
                fsw[w][c] = s;
            }
        }
        __syncthreads();
        if (t < 64) chsum[t] = fsw[0][t] + fsw[1][t] + fsw[2][t] + fsw[3][t];
        __syncthreads();
        if (t < 128) {
            float s = 0.f;
            for (int c = 0; c < 64; ++c) s = fmaf(W8[t * 64 + c], chsum[c], s);
            atomicAdd(&out_sasc[b * OC + t], s * (1.f / (float)LP));
        }
    }
}

extern "C" void kernel_launch(void* const* d_in, const int* in_sizes, int n_in,
                              void* d_out, int out_size, void* d_ws, size_t ws_size,
                              hipStream_t stream) {
    (void)in_sizes; (void)n_in; (void)out_size; (void)ws_size;
    const float* x    = (const float*)d_in[0];
    const float* W5a  = (const float*)d_in[1];
    const float* g5a  = (const float*)d_in[2];
    const float* b5a  = (const float*)d_in[3];
    const float* W5c  = (const float*)d_in[4];
    const float* g5c  = (const float*)d_in[5];
    const float* b5c  = (const float*)d_in[6];
    const float* Wq   = (const float*)d_in[7];
    const float* bq   = (const float*)d_in[8];
    const float* Wk   = (const float*)d_in[9];
    const float* bk   = (const float*)d_in[10];
    const float* Wv   = (const float*)d_in[11];
    const float* bv   = (const float*)d_in[12];
    const float* gpam = (const float*)d_in[13];
    const float* gcam = (const float*)d_in[14];
    const float* W51  = (const float*)d_in[15];
    const float* g51  = (const float*)d_in[16];
    const float* b51  = (const float*)d_in[17];
    const float* W52  = (const float*)d_in[18];
    const float* g52  = (const float*)d_in[19];
    const float* b52  = (const float*)d_in[20];
    const float* W6   = (const float*)d_in[21];
    const float* b6   = (const float*)d_in[22];
    const float* W7   = (const float*)d_in[23];
    const float* b7   = (const float*)d_in[24];
    const float* W8   = (const float*)d_in[25];
    const float* b8   = (const float*)d_in[26];

    float* ws = (float*)d_ws;
    float* out = (float*)d_out;
    unsigned short* Y1T  = (unsigned short*)(ws + OFF_Y1T);
    unsigned short* Y2C  = (unsigned short*)(ws + OFF_Y2C);
    unsigned short* SAFT = (unsigned short*)(ws + OFF_SAFT);
    unsigned short* SCFT = (unsigned short*)(ws + OFF_SCFT);
    unsigned short* Y51T = (unsigned short*)(ws + OFF_Y51T);
    unsigned short* Y52T = (unsigned short*)(ws + OFF_Y52T);
    unsigned short* VB   = (unsigned short*)(ws + OFF_VB);
    unsigned short* QT   = (unsigned short*)(ws + OFF_QT);
    unsigned short* KT   = (unsigned short*)(ws + OFF_KT);
    float* LPART  = ws + OFF_LPART;
    float* EPART  = ws + OFF_EPART;
    float* ATTN   = ws + OFF_ATTN;
    float* STATS1 = ws + OFF_STATS1;
    float* STATS2 = ws + OFF_STATS2;
    unsigned short* W5BF = (unsigned short*)(ws + OFF_W5BF);
    unsigned short* W67  = (unsigned short*)(ws + OFF_W67);
    unsigned short* WT   = (unsigned short*)(ws + OFF_WT);
    unsigned short* WQKV = (unsigned short*)(ws + OFF_WQKV);
    float* BQKV = ws + OFF_BQKV;

    float* out_sa = out + B * OC;
    float* out_sc = out + B * OC + (size_t)B * OC * LP;
    unsigned short* OPART = (unsigned short*)out_sa;  // scratch, overwritten by k_final

    k_wprep<<<321, 256, 0, stream>>>(W5a, W5c, W6, W7, W51, W52, Wq, Wk, Wv,
                                     bq, bk, bv, b8, W5BF, W67, WT, WQKV, BQKV,
                                     STATS1, STATS2, out);
    k_conv1<<<dim3(128, B), 256, 0, stream>>>(x, W5BF, Y1T, Y2C, STATS1);
    k_fuse1<<<288, 256, 512, stream>>>(Y1T, Y2C, STATS1, g5a, b5a, g5c, b5c,
                                       WQKV, BQKV, QT, KT, VB, EPART);
    k_fuse2<<<1032, 256, 18432, stream>>>(QT, KT, VB, OPART, LPART, EPART, ATTN);
    k_fuse3<<<384, 256, 33792, stream>>>(OPART, LPART, Y1T, Y2C, STATS1,
                                         g5a, b5a, g5c, b5c, gpam, gcam, ATTN,
                                         SAFT, SCFT);
    k_conv3<<<dim3(32, 2, B), 256, 0, stream>>>(SAFT, SCFT, WT, Y51T, Y52T, STATS2);
    k_final<<<dim3(32, 2, B), 256, 0, stream>>>(Y51T, Y52T, STATS2, g51, b51, g52, b52,
                                                W67, b6, b7, W8, out_sa, out_sc, out);
}

// Round 8
// 235.521 us; speedup vs baseline: 1.1642x; 1.1642x over previous
//
#include <hip/hip_runtime.h>
#include <math.h>

#define B 8
#define C 256
#define L 2046
#define LP 2048
#define IC 64
#define OC 128
#define BN_EPS 1e-5f
#define INVN (1.f / 16384.f)   // 1/(B*LP)

// ws offsets (float units)
#define OFF_Y1T    0u          // conv1 out (pre-BN) bf16 [b][l][64]
#define OFF_Y2C    524288u     // conv1 out (pre-BN) bf16 [b][64][l]
#define OFF_SAFT   1048576u    // sa_feat bf16 [b][l][64]
#define OFF_SCFT   1572864u    // sc_feat bf16 [b][l][64]
#define OFF_Y51T   2097152u    // conv3 out (pre-BN) bf16 [b][l][64]
#define OFF_Y52T   2621440u
#define OFF_VB     3145728u    // v bf16 [b][64][l]
#define OFF_QT     3670016u    // q bf16 [b][l][8]
#define OFF_KT     3735552u
#define OFF_LPART  3801088u    // pam denominators [b][32][4][64]
#define OFF_EPART  3866624u    // CAM gram partials [b][16][64][64]
#define OFF_ATTN   4390912u
#define OFF_STATS1 4423680u    // [4 copies][128ch][2] atomic sum/sumsq
#define OFF_STATS2 4424704u
#define OFF_W5BF   4425728u    // bf16 [128][256]
#define OFF_W67    4442112u    // bf16 [2][128][64]
#define OFF_WT     4450304u    // bf16 [2][3][64][64]
#define OFF_WQKV   4462592u    // bf16 [80][64]
#define OFF_BQKV   4465152u    // fp32 [80]

typedef __attribute__((ext_vector_type(8))) short bshort8;
typedef __attribute__((ext_vector_type(4))) float f32x4;

// fast bf16 round-half-up (differs from RTNE only on exact ties)
__device__ __forceinline__ unsigned short f2bf(float f) {
    union { float f; unsigned int u; } v; v.f = f;
    return (unsigned short)((v.u + 0x8000u) >> 16);
}
__device__ __forceinline__ float bf2f(unsigned short u) {
    union { unsigned int i; float f; } v; v.i = ((unsigned int)u) << 16;
    return v.f;
}
// pack two floats' rounded bf16: low16 from a, high16 from b
__device__ __forceinline__ unsigned int pk2(float a, float b) {
    union { float f; unsigned int u; } va, vb; va.f = a; vb.f = b;
    return __builtin_amdgcn_perm(vb.u + 0x8000u, va.u + 0x8000u, 0x07060302u);
}

// BN affine coefs from 4-copy atomic stats
__device__ __forceinline__ void load_coef(const float* __restrict__ STATS,
        const float* __restrict__ g, const float* __restrict__ beta,
        int base, int cnt, float* cA, float* cB) {
    int t = threadIdx.x;
    if (t < cnt) {
        int ch = base + t;
        float s = STATS[ch * 2] + STATS[256 + ch * 2] + STATS[512 + ch * 2] + STATS[768 + ch * 2];
        float q = STATS[ch * 2 + 1] + STATS[256 + ch * 2 + 1] + STATS[512 + ch * 2 + 1] + STATS[768 + ch * 2 + 1];
        float mu = s * INVN;
        float var = q * INVN - mu * mu;
        float A = g[t] * rsqrtf(var + BN_EPS);
        cA[t] = A;
        cB[t] = beta[t] - mu * A;
    }
}

// ---- weight prep + stats zero + out b8-init ----
__global__ __launch_bounds__(256) void k_wprep(
        const float* __restrict__ W5a, const float* __restrict__ W5c,
        const float* __restrict__ W6, const float* __restrict__ W7,
        const float* __restrict__ W51, const float* __restrict__ W52,
        const float* __restrict__ Wq, const float* __restrict__ Wk,
        const float* __restrict__ Wv, const float* __restrict__ bq,
        const float* __restrict__ bk, const float* __restrict__ bv,
        const float* __restrict__ b8,
        unsigned short* __restrict__ W5BF, unsigned short* __restrict__ W67,
        unsigned short* __restrict__ WT, unsigned short* __restrict__ WQKV,
        float* __restrict__ BQKV, float* __restrict__ STATS1,
        float* __restrict__ STATS2, float* __restrict__ out_sasc) {
    int i = blockIdx.x * 256 + threadIdx.x;
    if (i < 32768) {
        int o = i >> 8, c = i & 255;
        W5BF[i] = f2bf(o < 64 ? W5a[o * 256 + c] : W5c[(o - 64) * 256 + c]);
    } else if (i < 49152) {
        int j = i - 32768; int g = j >> 13; int r = j & 8191;
        W67[j] = f2bf(g ? W7[r] : W6[r]);
    } else if (i < 73728) {
        int j = i - 49152;
        int c = j & 63, o = (j >> 6) & 63, wt = j >> 12; int w = wt / 3, t = wt % 3;
        const float* Ws = w ? W52 : W51;
        WT[j] = f2bf(Ws[(o * 64 + c) * 3 + t]);
    } else if (i < 78848) {
        int j = i - 73728; int o = j >> 6, c = j & 63;
        float v = o < 8 ? Wq[o * 64 + c] : (o < 16 ? Wk[(o - 8) * 64 + c] : Wv[(o - 16) * 64 + c]);
        WQKV[j] = f2bf(v);
    } else if (i < 78928) {
        int o = i - 78848;
        BQKV[o] = o < 8 ? bq[o] : (o < 16 ? bk[o - 8] : bv[o - 16]);
    } else if (i < 80976) {
        int j = i - 78928;
        if (j < 1024) STATS1[j] = 0.f; else STATS2[j - 1024] = 0.f;
    } else if (i < 82000) {
        int j = i - 80976;
        out_sasc[j] = b8[j & 127];
    }
}

// ---- conv1x1(x): single coalesced x pass; pre-BN bf16 + atomic stats ----
// grid (32, B), 256 thr. 64-l tile staged to LDS as bf16 [l][c].
// MFMA: wave w -> output chans {2w*16..}, waves 0,1 -> branch A (Y1T),
// waves 2,3 -> branch B (Y2C); 4 l-subtiles each.
__global__ __launch_bounds__(256) void k_conv1(const float* __restrict__ x,
        const unsigned short* __restrict__ W5BF,
        unsigned short* __restrict__ Y1T, unsigned short* __restrict__ Y2C,
        float* __restrict__ STATS1) {
    __shared__ unsigned short xt[64][264];   // [l][c] bf16, row 528B (16B-aligned)
    __shared__ float lds_part[4][64];
    int lt = blockIdx.x, b = blockIdx.y;
    int l0 = lt * 64;
    int t = threadIdx.x;
    {   // stage: lane j = l offset (coalesced 256B per channel row), cg = channel quarter
        int j = t & 63, cg = t >> 6;
        int ls = l0 - 1 + j;
        bool ok = (ls >= 0) && (ls < L);
        const float* xs = x + (size_t)(b * C + cg * 64) * L + ls;
        unsigned short* row = &xt[j][cg * 64];
#pragma unroll 8
        for (int cc = 0; cc < 64; ++cc) {
            float v = ok ? xs[(size_t)cc * L] : 0.f;
            row[cc] = f2bf(v);
        }
    }
    __syncthreads();
    int w = t >> 6, lane = t & 63, n = lane & 15, quad = lane >> 4;
    // hoist W fragments (L2-resident, 16 x 16B)
    bshort8 wf[2][8];
#pragma unroll
    for (int oi = 0; oi < 2; ++oi)
#pragma unroll
        for (int kt = 0; kt < 8; ++kt)
            wf[oi][kt] = *(const bshort8*)(W5BF + (size_t)((w * 2 + oi) * 16 + n) * C + kt * 32 + quad * 8);
    f32x4 acc[2][4];
#pragma unroll
    for (int oi = 0; oi < 2; ++oi)
#pragma unroll
        for (int sub = 0; sub < 4; ++sub) acc[oi][sub] = (f32x4){0.f, 0.f, 0.f, 0.f};
#pragma unroll
    for (int sub = 0; sub < 4; ++sub) {
        int lloc = sub * 16 + n;
#pragma unroll
        for (int kt = 0; kt < 8; ++kt) {
            bshort8 xb = *(const bshort8*)(&xt[lloc][kt * 32 + quad * 8]);
            acc[0][sub] = __builtin_amdgcn_mfma_f32_16x16x32_bf16(wf[0][kt], xb, acc[0][sub], 0, 0, 0);
            acc[1][sub] = __builtin_amdgcn_mfma_f32_16x16x32_bf16(wf[1][kt], xb, acc[1][sub], 0, 0, 0);
        }
    }
    if (w < 2) {
#pragma unroll
        for (int sub = 0; sub < 4; ++sub) {
            int lp = l0 + sub * 16 + n;
#pragma unroll
            for (int oi = 0; oi < 2; ++oi) {
                int ot = w * 2 + oi;
                uint2 pv;
                pv.x = pk2(acc[oi][sub][0], acc[oi][sub][1]);
                pv.y = pk2(acc[oi][sub][2], acc[oi][sub][3]);
                *(uint2*)(Y1T + ((size_t)(b * LP + lp)) * IC + ot * 16 + quad * 4) = pv;
            }
        }
    } else {
#pragma unroll
        for (int oi = 0; oi < 2; ++oi) {
            int ot = (w - 2) * 2 + oi;
#pragma unroll
            for (int r = 0; r < 4; ++r) {
                int o = ot * 16 + quad * 4 + r;
                unsigned short* dst = Y2C + ((size_t)(b * IC + o)) * LP + l0;
#pragma unroll
                for (int sub = 0; sub < 4; ++sub)
                    dst[sub * 16 + n] = f2bf(acc[oi][sub][r]);
            }
        }
    }
    // stats: per wave 32 channels; sum over subtiles then lane-reduce over n
#pragma unroll
    for (int oi = 0; oi < 2; ++oi)
#pragma unroll
        for (int r = 0; r < 4; ++r) {
            float s = 0.f, q = 0.f;
#pragma unroll
            for (int sub = 0; sub < 4; ++sub) {
                float v = acc[oi][sub][r];
                s += v; q += v * v;
            }
#pragma unroll
            for (int msk = 1; msk < 16; msk <<= 1) {
                s += __shfl_xor(s, msk, 64);
                q += __shfl_xor(q, msk, 64);
            }
            if (n == 0) {
                int ci = oi * 16 + quad * 4 + r;   // 0..31 within wave
                lds_part[w][ci * 2] = s;
                lds_part[w][ci * 2 + 1] = q;
            }
        }
    __syncthreads();
    {   // ch = t>>1 (0..127); wave covering it = ch>>5
        int ch = t >> 1, wsrc = ch >> 5;
        int idx = ((ch & 31) << 1) | (t & 1);
        atomicAdd(&STATS1[(blockIdx.x & 3) * 256 + t], lds_part[wsrc][idx]);
    }
}

// ================= fuse1: qkv (256 blocks) | gram (32 blocks) =================
__device__ void role_qkv(char* dynsm, int lt, int b,
        const unsigned short* __restrict__ Y1T, const float* __restrict__ STATS1,
        const float* __restrict__ g5a, const float* __restrict__ b5a,
        const unsigned short* __restrict__ WQKV, const float* __restrict__ BQKV,
        unsigned short* __restrict__ QT, unsigned short* __restrict__ KT,
        unsigned short* __restrict__ VB) {
    float* cA = (float*)dynsm;
    float* cB = cA + 64;
    load_coef(STATS1, g5a, b5a, 0, 64, cA, cB);
    __syncthreads();
    int t = threadIdx.x;
    int w = t >> 6, lane = t & 63, n = lane & 15, quad = lane >> 4;
    int lrow = lt * 64 + w * 16 + n;
    bshort8 fb[2];
#pragma unroll
    for (int kt = 0; kt < 2; ++kt) {
        bshort8 raw = *(const bshort8*)(Y1T + ((size_t)(b * LP + lrow)) * IC + kt * 32 + quad * 8);
        bshort8 f;
#pragma unroll
        for (int j = 0; j < 8; ++j) {
            int c = kt * 32 + quad * 8 + j;
            float v = fmaxf(fmaf(cA[c], bf2f((unsigned short)raw[j]), cB[c]), 0.f);
            ((unsigned short*)&f)[j] = f2bf(v);
        }
        fb[kt] = f;
    }
    f32x4 acc[5];
#pragma unroll
    for (int ot = 0; ot < 5; ++ot) {
        f32x4 a = {0.f, 0.f, 0.f, 0.f};
#pragma unroll
        for (int kt = 0; kt < 2; ++kt) {
            bshort8 wf = *(const bshort8*)(WQKV + (size_t)(ot * 16 + n) * IC + kt * 32 + quad * 8);
            a = __builtin_amdgcn_mfma_f32_16x16x32_bf16(wf, fb[kt], a, 0, 0, 0);
        }
        acc[ot] = a;
    }
#pragma unroll
    for (int ot = 0; ot < 5; ++ot)
#pragma unroll
        for (int r = 0; r < 4; ++r) {
            int o = ot * 16 + quad * 4 + r;
            unsigned short bv16 = f2bf(acc[ot][r] + BQKV[o]);
            if (ot == 0) {
                if (o < 8) QT[((size_t)(b * LP + lrow)) * 8 + o] = bv16;
                else KT[((size_t)(b * LP + lrow)) * 8 + (o - 8)] = bv16;
            } else {
                VB[((size_t)(b * IC + (o - 16))) * LP + lrow] = bv16;
            }
        }
}

__device__ void role_gram(char* dynsm, int blk, int b,
        const unsigned short* __restrict__ Y2C, const float* __restrict__ STATS1,
        const float* __restrict__ g5c, const float* __restrict__ b5c,
        float* __restrict__ EPART) {
    float* cA = (float*)dynsm;
    float* cB = cA + 64;
    load_coef(STATS1, g5c, b5c, 64, 64, cA, cB);
    __syncthreads();
    int t = threadIdx.x;
    int w = t >> 6, lane = t & 63, n = lane & 15, quad = lane >> 4;
    f32x4 acc[4][4];
#pragma unroll
    for (int ti = 0; ti < 4; ++ti)
#pragma unroll
        for (int tj = 0; tj < 4; ++tj) acc[ti][tj] = (f32x4){0.f, 0.f, 0.f, 0.f};
    for (int chunk = 0; chunk < 4; ++chunk) {
        int lb = (blk * 4 + w) * 128 + chunk * 32 + quad * 8;
        bshort8 frag[4];
#pragma unroll
        for (int g = 0; g < 4; ++g) {
            int c = g * 16 + n;
            bshort8 raw = *(const bshort8*)(Y2C + ((size_t)(b * IC + c)) * LP + lb);
            bshort8 f;
            float A = cA[c], Bc = cB[c];
#pragma unroll
            for (int j = 0; j < 8; ++j)
                ((unsigned short*)&f)[j] = f2bf(fmaxf(fmaf(A, bf2f((unsigned short)raw[j]), Bc), 0.f));
            frag[g] = f;
        }
#pragma unroll
        for (int ti = 0; ti < 4; ++ti)
#pragma unroll
            for (int tj = 0; tj < 4; ++tj)
                acc[ti][tj] = __builtin_amdgcn_mfma_f32_16x16x32_bf16(frag[ti], frag[tj], acc[ti][tj], 0, 0, 0);
    }
    float* ep = EPART + ((size_t)(b * 16 + blk * 4 + w)) * 4096;
#pragma unroll
    for (int ti = 0; ti < 4; ++ti)
#pragma unroll
        for (int tj = 0; tj < 4; ++tj)
#pragma unroll
            for (int r = 0; r < 4; ++r)
                ep[(ti * 16 + quad * 4 + r) * 64 + tj * 16 + n] = acc[ti][tj][r];
}

__global__ __launch_bounds__(256) void k_fuse1(
        const unsigned short* __restrict__ Y1T, const unsigned short* __restrict__ Y2C,
        const float* __restrict__ STATS1,
        const float* __restrict__ g5a, const float* __restrict__ b5a,
        const float* __restrict__ g5c, const float* __restrict__ b5c,
        const unsigned short* __restrict__ WQKV, const float* __restrict__ BQKV,
        unsigned short* __restrict__ QT, unsigned short* __restrict__ KT,
        unsigned short* __restrict__ VB, float* __restrict__ EPART) {
    extern __shared__ char dynsm[];
    int idx = blockIdx.x;
    if (idx < 256) role_qkv(dynsm, idx & 31, idx >> 5, Y1T, STATS1, g5a, b5a,
                            WQKV, BQKV, QT, KT, VB);
    else { int g = idx - 256; role_gram(dynsm, g & 3, g >> 2, Y2C, STATS1, g5c, b5c, EPART); }
}

// ================= fuse2: pam (1024 blocks) | cam_softmax (8) =================
__device__ void role_pam(char* dynsm, int qt, int ks, int b,
        const unsigned short* __restrict__ qT, const unsigned short* __restrict__ kT,
        const unsigned short* __restrict__ vb,
        unsigned short* __restrict__ OPART, float* __restrict__ LPART) {
    unsigned short* vs = (unsigned short*)dynsm;      // [64][72]
    unsigned short* ps = vs + 4608;                   // 4 x [16][72]
    float* os = (float*)dynsm;                        // [64][65] aliased after loop
    int l0 = qt * 64;
    int tid = threadIdx.x;
    int wq = tid >> 6, lane = tid & 63, n = lane & 15, quad = lane >> 4;
    bshort8 qa = {};
    if (quad == 0)
        qa = *(const bshort8*)(qT + ((size_t)(b * LP + l0 + wq * 16 + n)) * 8);
    f32x4 acc[4];
#pragma unroll
    for (int s = 0; s < 4; ++s) acc[s] = (f32x4){0.f, 0.f, 0.f, 0.f};
    float li[4] = {0.f, 0.f, 0.f, 0.f};
    unsigned short* pw = ps + wq * 16 * 72;

    for (int it = 0; it < 8; ++it) {
        int m0 = ks * 512 + it * 64;
        __syncthreads();
        {
            int row = tid >> 2, chn = tid & 3;
            const unsigned short* src = vb + ((size_t)(b * IC + row)) * LP + m0 + chn * 16;
            unsigned short* dstl = vs + row * 72 + chn * 16;
            *(bshort8*)dstl = *(const bshort8*)src;
            *(bshort8*)(dstl + 8) = *(const bshort8*)(src + 8);
        }
        bshort8 kb[4];
#pragma unroll
        for (int s = 0; s < 4; ++s) kb[s] = (bshort8){};
        if (quad == 0) {
#pragma unroll
            for (int s = 0; s < 4; ++s)
                kb[s] = *(const bshort8*)(kT + ((size_t)(b * LP + m0 + s * 16 + n)) * 8);
        }
        __syncthreads();
        f32x4 sc[4];
#pragma unroll
        for (int s = 0; s < 4; ++s)
            sc[s] = __builtin_amdgcn_mfma_f32_16x16x32_bf16(qa, kb[s],
                        (f32x4){0.f, 0.f, 0.f, 0.f}, 0, 0, 0);
#pragma unroll
        for (int s = 0; s < 4; ++s)
#pragma unroll
            for (int r = 0; r < 4; ++r) {
                float p = __expf(sc[s][r]);
                li[r] += p;
                pw[(quad * 4 + r) * 72 + s * 16 + n] = f2bf(p);
            }
#pragma unroll
        for (int step = 0; step < 2; ++step) {
            bshort8 pa = *(const bshort8*)(pw + n * 72 + step * 32 + quad * 8);
#pragma unroll
            for (int s = 0; s < 4; ++s) {
                bshort8 vf = *(const bshort8*)(vs + (s * 16 + n) * 72 + step * 32 + quad * 8);
                acc[s] = __builtin_amdgcn_mfma_f32_16x16x32_bf16(pa, vf, acc[s], 0, 0, 0);
            }
        }
    }
    __syncthreads();
#pragma unroll
    for (int s = 0; s < 4; ++s)
#pragma unroll
        for (int r = 0; r < 4; ++r)
            os[(s * 16 + n) * 65 + wq * 16 + quad * 4 + r] = acc[s][r];
    size_t lbase = ((size_t)((b * 32 + qt) * 4 + ks)) * 64;
#pragma unroll
    for (int r = 0; r < 4; ++r) {
        float s_ = li[r];
#pragma unroll
        for (int msk = 1; msk < 16; msk <<= 1) s_ += __shfl_xor(s_, msk, 64);
        if (n == 0) LPART[lbase + wq * 16 + quad * 4 + r] = s_;
    }
    __syncthreads();
    size_t ob = ((size_t)((b * 32 + qt) * 4 + ks)) * 4096;
    int c = tid >> 2, qc = tid & 3;
    unsigned int* od = (unsigned int*)(OPART + ob + c * 64 + qc * 16);
#pragma unroll
    for (int i = 0; i < 8; ++i)
        od[i] = pk2(os[c * 65 + qc * 16 + 2 * i], os[c * 65 + qc * 16 + 2 * i + 1]);
}

__device__ void role_cam_softmax(char* dynsm, int b,
        const float* __restrict__ EPART, float* __restrict__ attn) {
    float* e = (float*)dynsm;
    int t = threadIdx.x;
    for (int idx = t; idx < 4096; idx += 256) {
        float s = 0.f;
        for (int ch = 0; ch < 16; ++ch) s += EPART[((size_t)(b * 16 + ch)) * 4096 + idx];
        e[idx] = s;
    }
    __syncthreads();
    if (t < 64) {
        float mn = INFINITY;
        for (int d = 0; d < 64; ++d) mn = fminf(mn, e[t * 64 + d]);
        float s = 0.f;
        float* a = attn + (size_t)b * 4096 + t * 64;
        for (int d = 0; d < 64; ++d) { float p = __expf(mn - e[t * 64 + d]); a[d] = p; s += p; }
        float inv = 1.f / s;
        for (int d = 0; d < 64; ++d) a[d] *= inv;
    }
}

__global__ __launch_bounds__(256) void k_fuse2(
        const unsigned short* __restrict__ QT, const unsigned short* __restrict__ KT,
        const unsigned short* __restrict__ VB,
        unsigned short* __restrict__ OPART, float* __restrict__ LPART,
        const float* __restrict__ EPART, float* __restrict__ ATTN) {
    extern __shared__ char dynsm[];
    int idx = blockIdx.x;
    if (idx < 1024) role_pam(dynsm, idx & 31, (idx >> 5) & 3, idx >> 7, QT, KT, VB, OPART, LPART);
    else role_cam_softmax(dynsm, idx - 1024, EPART, ATTN);
}

// ============ fuse3: pam_combine (256 blocks) | cam_apply (128) ============
__device__ void role_pam_combine(char* dynsm, int qt, int b,
        const unsigned short* __restrict__ OPART, const float* __restrict__ LPART,
        const unsigned short* __restrict__ Y1T, const float* __restrict__ STATS1,
        const float* __restrict__ g5a, const float* __restrict__ b5a,
        const float* __restrict__ gamma, unsigned short* __restrict__ SAFT) {
    float* dn = (float*)dynsm;
    float* cA = dn + 64;
    float* cB = cA + 64;
    unsigned short* tile = (unsigned short*)(cB + 64);   // 64*66
    int l0 = qt * 64;
    int t = threadIdx.x;
    load_coef(STATS1, g5a, b5a, 0, 64, cA, cB);
    if (t < 64) {
        size_t lbase = ((size_t)((b * 32 + qt) * 4)) * 64;
        dn[t] = LPART[lbase + t] + LPART[lbase + 64 + t] +
                LPART[lbase + 128 + t] + LPART[lbase + 192 + t];
    }
    __syncthreads();
    int c = t >> 2, qc = t & 3;
    float O[16];
#pragma unroll
    for (int i = 0; i < 16; ++i) O[i] = 0.f;
    size_t ob = ((size_t)((b * 32 + qt) * 4)) * 4096 + c * 64 + qc * 16;
#pragma unroll
    for (int s = 0; s < 4; ++s) {
        bshort8 p0 = *(const bshort8*)(OPART + ob + (size_t)s * 4096);
        bshort8 p1 = *(const bshort8*)(OPART + ob + (size_t)s * 4096 + 8);
#pragma unroll
        for (int i = 0; i < 8; ++i) {
            O[i]     += bf2f((unsigned short)p0[i]);
            O[8 + i] += bf2f((unsigned short)p1[i]);
        }
    }
    float gm = gamma[0];
#pragma unroll
    for (int i = 0; i < 16; ++i) {
        int q = qc * 16 + i;
        unsigned short raw = Y1T[((size_t)(b * LP + l0 + q)) * IC + c];
        float f1v = fmaxf(fmaf(cA[c], bf2f(raw), cB[c]), 0.f);
        float val = fmaf(gm, O[i] / dn[q], f1v);
        tile[q * 66 + c] = f2bf(val);
    }
    __syncthreads();
    int li = t >> 2, cc = t & 3;
    unsigned int* dst = (unsigned int*)(SAFT + ((size_t)(b * LP + l0 + li)) * IC + cc * 16);
#pragma unroll
    for (int i = 0; i < 8; ++i)
        dst[i] = *(unsigned int*)(tile + li * 66 + cc * 16 + 2 * i);
}

__device__ void role_cam_apply(char* dynsm, int blkx, int b,
        const float* __restrict__ attn, const unsigned short* __restrict__ Y2C,
        const float* __restrict__ STATS1,
        const float* __restrict__ g5c, const float* __restrict__ b5c,
        const float* __restrict__ gamma, unsigned short* __restrict__ SCFT) {
    float* as = (float*)dynsm;                    // 4096 floats
    float* cA = as + 4096;
    float* cB = cA + 64;
    unsigned short* tile = (unsigned short*)(cB + 64);  // 128*66
    int l0 = blkx * 128;
    int t = threadIdx.x;
    int lq = t & 127, ch = t >> 7;
    load_coef(STATS1, g5c, b5c, 64, 64, cA, cB);
    for (int i = t; i < 4096; i += 256) as[i] = attn[(size_t)b * 4096 + i];
    __syncthreads();
    float acc[32];
#pragma unroll
    for (int i = 0; i < 32; ++i) acc[i] = 0.f;
    const unsigned short* fb = Y2C + (size_t)b * IC * LP + l0 + lq;
    for (int d4 = 0; d4 < 16; ++d4) {
        float fv[4];
#pragma unroll
        for (int i = 0; i < 4; ++i) {
            int d = 4 * d4 + i;
            fv[i] = fmaxf(fmaf(cA[d], bf2f(fb[(size_t)d * LP]), cB[d]), 0.f);
        }
#pragma unroll
        for (int cc = 0; cc < 32; ++cc) {
            const float4 a4 = *reinterpret_cast<const float4*>(as + (ch * 32 + cc) * 64 + d4 * 4);
            acc[cc] += a4.x * fv[0] + a4.y * fv[1] + a4.z * fv[2] + a4.w * fv[3];
        }
    }
    float gm = gamma[0];
#pragma unroll
    for (int cc = 0; cc < 32; ++cc) {
        int c = ch * 32 + cc;
        float res = fmaxf(fmaf(cA[c], bf2f(fb[(size_t)c * LP]), cB[c]), 0.f);
        tile[lq * 66 + c] = f2bf(fmaf(gm, acc[cc], res));
    }
    __syncthreads();
    int li = t >> 1, half = t & 1;
    unsigned int* dst = (unsigned int*)(SCFT + ((size_t)(b * LP + l0 + li)) * IC + half * 32);
#pragma unroll
    for (int i = 0; i < 16; ++i)
        dst[i] = *(unsigned int*)(tile + li * 66 + half * 32 + 2 * i);
}

__global__ __launch_bounds__(256) void k_fuse3(
        const unsigned short* __restrict__ OPART, const float* __restrict__ LPART,
        const unsigned short* __restrict__ Y1T, const unsigned short* __restrict__ Y2C,
        const float* __restrict__ STATS1,
        const float* __restrict__ g5a, const float* __restrict__ b5a,
        const float* __restrict__ g5c, const float* __restrict__ b5c,
        const float* __restrict__ gpam, const float* __restrict__ gcam,
        const float* __restrict__ ATTN,
        unsigned short* __restrict__ SAFT, unsigned short* __restrict__ SCFT) {
    extern __shared__ char dynsm[];
    int idx = blockIdx.x;
    if (idx < 256) role_pam_combine(dynsm, idx & 31, idx >> 5, OPART, LPART, Y1T,
                                    STATS1, g5a, b5a, gpam, SAFT);
    else { int g = idx - 256; role_cam_apply(dynsm, g & 15, g >> 4, ATTN, Y2C,
                                             STATS1, g5c, b5c, gcam, SCFT); }
}

// ---- conv3 (both branches) -> pre-BN bf16 + atomic stats ----
__global__ __launch_bounds__(256) void k_conv3(const unsigned short* __restrict__ SAFT,
        const unsigned short* __restrict__ SCFT, const unsigned short* __restrict__ WTall,
        unsigned short* __restrict__ Y51T, unsigned short* __restrict__ Y52T,
        float* __restrict__ STATS2) {
    __shared__ float lds_part[4][128];
    int lt = blockIdx.x, og = blockIdx.y, b = blockIdx.z;
    const unsigned short* FTsrc = og ? SCFT : SAFT;
    const unsigned short* WT = WTall + og * 12288;
    unsigned short* dst = og ? Y52T : Y51T;
    int l0 = lt * 64;
    int w = threadIdx.x >> 6, lane = threadIdx.x & 63, n = lane & 15, quad = lane >> 4;
    int lrow = l0 + w * 16 + n;
    f32x4 acc[4];
#pragma unroll
    for (int ot = 0; ot < 4; ++ot) acc[ot] = (f32x4){0.f, 0.f, 0.f, 0.f};
#pragma unroll
    for (int t3 = 0; t3 < 3; ++t3) {
        int row = lrow + t3 - 1;
        bshort8 fb[2];
#pragma unroll
        for (int kt = 0; kt < 2; ++kt) {
            if (row >= 0 && row < LP)
                fb[kt] = *(const bshort8*)(FTsrc + ((size_t)(b * LP + row)) * IC + kt * 32 + quad * 8);
            else fb[kt] = (bshort8){};
        }
#pragma unroll
        for (int ot = 0; ot < 4; ++ot)
#pragma unroll
            for (int kt = 0; kt < 2; ++kt) {
                bshort8 wf = *(const bshort8*)(WT + ((size_t)(t3 * 64 + ot * 16 + n)) * IC + kt * 32 + quad * 8);
                acc[ot] = __builtin_amdgcn_mfma_f32_16x16x32_bf16(wf, fb[kt], acc[ot], 0, 0, 0);
            }
    }
#pragma unroll
    for (int ot = 0; ot < 4; ++ot) {
        uint2 pv;
        pv.x = pk2(acc[ot][0], acc[ot][1]);
        pv.y = pk2(acc[ot][2], acc[ot][3]);
        *(uint2*)(dst + ((size_t)(b * LP + lrow)) * IC + ot * 16 + quad * 4) = pv;
    }
#pragma unroll
    for (int ot = 0; ot < 4; ++ot)
#pragma unroll
        for (int r = 0; r < 4; ++r) {
            float s = acc[ot][r], q = s * s;
#pragma unroll
            for (int msk = 1; msk < 16; msk <<= 1) {
                s += __shfl_xor(s, msk, 64);
                q += __shfl_xor(q, msk, 64);
            }
            if (n == 0) {
                int cch = ot * 16 + quad * 4 + r;
                lds_part[w][cch * 2] = s;
                lds_part[w][cch * 2 + 1] = q;
            }
        }
    __syncthreads();
    int t = threadIdx.x;
    if (t < 128) {
        float s = lds_part[0][t] + lds_part[1][t] + lds_part[2][t] + lds_part[3][t];
        atomicAdd(&STATS2[(blockIdx.x & 3) * 256 + og * 128 + t], s);
    }
}

// ---- final conv1x1 pair + fused sasc projection (out pre-initialized to b8) ----
__global__ __launch_bounds__(256) void k_final(const unsigned short* __restrict__ Y51T,
        const unsigned short* __restrict__ Y52T, const float* __restrict__ STATS2,
        const float* __restrict__ g51, const float* __restrict__ b51,
        const float* __restrict__ g52, const float* __restrict__ b52,
        const unsigned short* __restrict__ W67,
        const float* __restrict__ b6, const float* __restrict__ b7,
        const float* __restrict__ W8,
        float* __restrict__ out_sa, float* __restrict__ out_sc,
        float* __restrict__ out_sasc) {
    __shared__ float cA[128], cB[128];
    __shared__ float fsw[4][64];
    __shared__ float chsum[64];
    int lt = blockIdx.x, og = blockIdx.y, b = blockIdx.z;
    int t = threadIdx.x;
    if (t < 128) {
        float s = STATS2[t * 2] + STATS2[256 + t * 2] + STATS2[512 + t * 2] + STATS2[768 + t * 2];
        float q = STATS2[t * 2 + 1] + STATS2[256 + t * 2 + 1] + STATS2[512 + t * 2 + 1] + STATS2[768 + t * 2 + 1];
        float mu = s * INVN, var = q * INVN - mu * mu;
        float gv = t < 64 ? g51[t] : g52[t - 64];
        float bv = t < 64 ? b51[t] : b52[t - 64];
        float A = gv * rsqrtf(var + BN_EPS);
        cA[t] = A; cB[t] = bv - mu * A;
    }
    __syncthreads();
    int w = t >> 6, lane = t & 63, n = lane & 15, quad = lane >> 4;
    int lrow = lt * 64 + w * 16 + n;
    float fs_lane[16];
    bshort8 ba[2], bb[2];
#pragma unroll
    for (int kt = 0; kt < 2; ++kt) {
        bshort8 ra = *(const bshort8*)(Y51T + ((size_t)(b * LP + lrow)) * IC + kt * 32 + quad * 8);
        bshort8 rb = *(const bshort8*)(Y52T + ((size_t)(b * LP + lrow)) * IC + kt * 32 + quad * 8);
        bshort8 fa, fb;
#pragma unroll
        for (int j = 0; j < 8; ++j) {
            int c = kt * 32 + quad * 8 + j;
            float v1 = fmaxf(fmaf(cA[c], bf2f((unsigned short)ra[j]), cB[c]), 0.f);
            float v2 = fmaxf(fmaf(cA[64 + c], bf2f((unsigned short)rb[j]), cB[64 + c]), 0.f);
            ((unsigned short*)&fa)[j] = f2bf(v1);
            ((unsigned short*)&fb)[j] = f2bf(v2);
            fs_lane[kt * 8 + j] = v1 + v2;
        }
        ba[kt] = fa; bb[kt] = fb;
    }
    f32x4 accA[4], accB[4];
#pragma unroll
    for (int ot = 0; ot < 4; ++ot) {
        accA[ot] = (f32x4){0.f, 0.f, 0.f, 0.f};
        accB[ot] = (f32x4){0.f, 0.f, 0.f, 0.f};
    }
#pragma unroll
    for (int ot = 0; ot < 4; ++ot)
#pragma unroll
        for (int kt = 0; kt < 2; ++kt) {
            bshort8 wa = *(const bshort8*)(W67 + (size_t)(og * 64 + ot * 16 + n) * IC + kt * 32 + quad * 8);
            bshort8 wb = *(const bshort8*)(W67 + 8192 + (size_t)(og * 64 + ot * 16 + n) * IC + kt * 32 + quad * 8);
            accA[ot] = __builtin_amdgcn_mfma_f32_16x16x32_bf16(wa, ba[kt], accA[ot], 0, 0, 0);
            accB[ot] = __builtin_amdgcn_mfma_f32_16x16x32_bf16(wb, bb[kt], accB[ot], 0, 0, 0);
        }
#pragma unroll
    for (int ot = 0; ot < 4; ++ot)
#pragma unroll
        for (int r = 0; r < 4; ++r) {
            int o = og * 64 + ot * 16 + quad * 4 + r;
            out_sa[((size_t)(b * OC + o)) * LP + lrow] = accA[ot][r] + b6[o];
            out_sc[((size_t)(b * OC + o)) * LP + lrow] = accB[ot][r] + b7[o];
        }
    if (og == 0) {
#pragma unroll
        for (int i = 0; i < 16; ++i) {
            float s = fs_lane[i];
#pragma unroll
            for (int msk = 1; msk < 16; msk <<= 1) s += __shfl_xor(s, msk, 64);
            if (n == 0) {
                int c = (i >> 3) * 32 + quad * 8 + (i & 7);
                fsw[w][c] = s;
            }
        }
        __syncthreads();
        if (t < 64) chsum[t] = fsw[0][t] + fsw[1][t] + fsw[2][t] + fsw[3][t];
        __syncthreads();
        if (t < 128) {
            float s = 0.f;
            for (int c = 0; c < 64; ++c) s = fmaf(W8[t * 64 + c], chsum[c], s);
            atomicAdd(&out_sasc[b * OC + t], s * (1.f / (float)LP));
        }
    }
}

extern "C" void kernel_launch(void* const* d_in, const int* in_sizes, int n_in,
                              void* d_out, int out_size, void* d_ws, size_t ws_size,
                              hipStream_t stream) {
    (void)in_sizes; (void)n_in; (void)out_size; (void)ws_size;
    const float* x    = (const float*)d_in[0];
    const float* W5a  = (const float*)d_in[1];
    const float* g5a  = (const float*)d_in[2];
    const float* b5a  = (const float*)d_in[3];
    const float* W5c  = (const float*)d_in[4];
    const float* g5c  = (const float*)d_in[5];
    const float* b5c  = (const float*)d_in[6];
    const float* Wq   = (const float*)d_in[7];
    const float* bq   = (const float*)d_in[8];
    const float* Wk   = (const float*)d_in[9];
    const float* bk   = (const float*)d_in[10];
    const float* Wv   = (const float*)d_in[11];
    const float* bv   = (const float*)d_in[12];
    const float* gpam = (const float*)d_in[13];
    const float* gcam = (const float*)d_in[14];
    const float* W51  = (const float*)d_in[15];
    const float* g51  = (const float*)d_in[16];
    const float* b51  = (const float*)d_in[17];
    const float* W52  = (const float*)d_in[18];
    const float* g52  = (const float*)d_in[19];
    const float* b52  = (const float*)d_in[20];
    const float* W6   = (const float*)d_in[21];
    const float* b6   = (const float*)d_in[22];
    const float* W7   = (const float*)d_in[23];
    const float* b7   = (const float*)d_in[24];
    const float* W8   = (const float*)d_in[25];
    const float* b8   = (const float*)d_in[26];

    float* ws = (float*)d_ws;
    float* out = (float*)d_out;
    unsigned short* Y1T  = (unsigned short*)(ws + OFF_Y1T);
    unsigned short* Y2C  = (unsigned short*)(ws + OFF_Y2C);
    unsigned short* SAFT = (unsigned short*)(ws + OFF_SAFT);
    unsigned short* SCFT = (unsigned short*)(ws + OFF_SCFT);
    unsigned short* Y51T = (unsigned short*)(ws + OFF_Y51T);
    unsigned short* Y52T = (unsigned short*)(ws + OFF_Y52T);
    unsigned short* VB   = (unsigned short*)(ws + OFF_VB);
    unsigned short* QT   = (unsigned short*)(ws + OFF_QT);
    unsigned short* KT   = (unsigned short*)(ws + OFF_KT);
    float* LPART  = ws + OFF_LPART;
    float* EPART  = ws + OFF_EPART;
    float* ATTN   = ws + OFF_ATTN;
    float* STATS1 = ws + OFF_STATS1;
    float* STATS2 = ws + OFF_STATS2;
    unsigned short* W5BF = (unsigned short*)(ws + OFF_W5BF);
    unsigned short* W67  = (unsigned short*)(ws + OFF_W67);
    unsigned short* WT   = (unsigned short*)(ws + OFF_WT);
    unsigned short* WQKV = (unsigned short*)(ws + OFF_WQKV);
    float* BQKV = ws + OFF_BQKV;

    float* out_sa = out + B * OC;
    float* out_sc = out + B * OC + (size_t)B * OC * LP;
    unsigned short* OPART = (unsigned short*)out_sa;  // scratch, overwritten by k_final

    k_wprep<<<321, 256, 0, stream>>>(W5a, W5c, W6, W7, W51, W52, Wq, Wk, Wv,
                                     bq, bk, bv, b8, W5BF, W67, WT, WQKV, BQKV,
                                     STATS1, STATS2, out);
    k_conv1<<<dim3(32, B), 256, 0, stream>>>(x, W5BF, Y1T, Y2C, STATS1);
    k_fuse1<<<288, 256, 512, stream>>>(Y1T, Y2C, STATS1, g5a, b5a, g5c, b5c,
                                       WQKV, BQKV, QT, KT, VB, EPART);
    k_fuse2<<<1032, 256, 18432, stream>>>(QT, KT, VB, OPART, LPART, EPART, ATTN);
    k_fuse3<<<384, 256, 33792, stream>>>(OPART, LPART, Y1T, Y2C, STATS1,
                                         g5a, b5a, g5c, b5c, gpam, gcam, ATTN,
                                         SAFT, SCFT);
    k_conv3<<<dim3(32, 2, B), 256, 0, stream>>>(SAFT, SCFT, WT, Y51T, Y52T, STATS2);
    k_final<<<dim3(32, 2, B), 256, 0, stream>>>(Y51T, Y52T, STATS2, g51, b51, g52, b52,
                                                W67, b6, b7, W8, out_sa, out_sc, out);
}

// Round 9
// 214.890 us; speedup vs baseline: 1.2760x; 1.0960x over previous
//
#include <hip/hip_runtime.h>
#include <math.h>

#define B 8
#define C 256
#define L 2046
#define LP 2048
#define IC 64
#define OC 128
#define BN_EPS 1e-5f
#define INVN (1.f / 16384.f)   // 1/(B*LP)

// ws offsets (float units)
#define OFF_Y1T    0u          // conv1 out (pre-BN) bf16 [b][l][64]
#define OFF_Y2C    524288u     // conv1 out (pre-BN) bf16 [b][64][l]
#define OFF_Y51T   2097152u    // conv3 out (pre-BN) bf16 [b][l][64]
#define OFF_Y52T   2621440u
#define OFF_VB     3145728u    // v bf16 [b][64][l]
#define OFF_QT     3670016u    // q bf16 [b][l][8]
#define OFF_KT     3735552u
#define OFF_LPART  3801088u    // pam denominators [b][32][4][64]
#define OFF_EPART  3866624u    // CAM gram partials [b][16][64][64]
#define OFF_ATTN   4390912u
#define OFF_STATS1 4423680u    // [4 copies][128ch][2] atomic sum/sumsq
#define OFF_STATS2 4424704u
#define OFF_W5BF   4425728u    // bf16 [128][256]
#define OFF_W67    4442112u    // bf16 [2][128][64]
#define OFF_WT     4450304u    // bf16 [2][3][64][64]
#define OFF_WQKV   4462592u    // bf16 [80][64]
#define OFF_BQKV   4465152u    // fp32 [80]

typedef __attribute__((ext_vector_type(8))) short bshort8;
typedef __attribute__((ext_vector_type(4))) float f32x4;

// fast bf16 round-half-up (differs from RTNE only on exact ties)
__device__ __forceinline__ unsigned short f2bf(float f) {
    union { float f; unsigned int u; } v; v.f = f;
    return (unsigned short)((v.u + 0x8000u) >> 16);
}
__device__ __forceinline__ float bf2f(unsigned short u) {
    union { unsigned int i; float f; } v; v.i = ((unsigned int)u) << 16;
    return v.f;
}
__device__ __forceinline__ unsigned int pk2(float a, float b) {
    union { float f; unsigned int u; } va, vb; va.f = a; vb.f = b;
    return __builtin_amdgcn_perm(vb.u + 0x8000u, va.u + 0x8000u, 0x07060302u);
}

// BN affine coefs from 4-copy atomic stats
__device__ __forceinline__ void load_coef(const float* __restrict__ STATS,
        const float* __restrict__ g, const float* __restrict__ beta,
        int base, int cnt, float* cA, float* cB) {
    int t = threadIdx.x;
    if (t < cnt) {
        int ch = base + t;
        float s = STATS[ch * 2] + STATS[256 + ch * 2] + STATS[512 + ch * 2] + STATS[768 + ch * 2];
        float q = STATS[ch * 2 + 1] + STATS[256 + ch * 2 + 1] + STATS[512 + ch * 2 + 1] + STATS[768 + ch * 2 + 1];
        float mu = s * INVN;
        float var = q * INVN - mu * mu;
        float A = g[t] * rsqrtf(var + BN_EPS);
        cA[t] = A;
        cB[t] = beta[t] - mu * A;
    }
}

// ---- weight prep + stats zero + out b8-init ----
__global__ __launch_bounds__(256) void k_wprep(
        const float* __restrict__ W5a, const float* __restrict__ W5c,
        const float* __restrict__ W6, const float* __restrict__ W7,
        const float* __restrict__ W51, const float* __restrict__ W52,
        const float* __restrict__ Wq, const float* __restrict__ Wk,
        const float* __restrict__ Wv, const float* __restrict__ bq,
        const float* __restrict__ bk, const float* __restrict__ bv,
        const float* __restrict__ b8,
        unsigned short* __restrict__ W5BF, unsigned short* __restrict__ W67,
        unsigned short* __restrict__ WT, unsigned short* __restrict__ WQKV,
        float* __restrict__ BQKV, float* __restrict__ STATS1,
        float* __restrict__ STATS2, float* __restrict__ out_sasc) {
    int i = blockIdx.x * 256 + threadIdx.x;
    if (i < 32768) {
        int o = i >> 8, c = i & 255;
        W5BF[i] = f2bf(o < 64 ? W5a[o * 256 + c] : W5c[(o - 64) * 256 + c]);
    } else if (i < 49152) {
        int j = i - 32768; int g = j >> 13; int r = j & 8191;
        W67[j] = f2bf(g ? W7[r] : W6[r]);
    } else if (i < 73728) {
        int j = i - 49152;
        int c = j & 63, o = (j >> 6) & 63, wt = j >> 12; int w = wt / 3, t = wt % 3;
        const float* Ws = w ? W52 : W51;
        WT[j] = f2bf(Ws[(o * 64 + c) * 3 + t]);
    } else if (i < 78848) {
        int j = i - 73728; int o = j >> 6, c = j & 63;
        float v = o < 8 ? Wq[o * 64 + c] : (o < 16 ? Wk[(o - 8) * 64 + c] : Wv[(o - 16) * 64 + c]);
        WQKV[j] = f2bf(v);
    } else if (i < 78928) {
        int o = i - 78848;
        BQKV[o] = o < 8 ? bq[o] : (o < 16 ? bk[o - 8] : bv[o - 16]);
    } else if (i < 80976) {
        int j = i - 78928;
        if (j < 1024) STATS1[j] = 0.f; else STATS2[j - 1024] = 0.f;
    } else if (i < 82000) {
        int j = i - 80976;
        out_sasc[j] = b8[j & 127];
    }
}

// ---- conv1x1(x): single coalesced x pass; pre-BN bf16 + atomic stats ----
__global__ __launch_bounds__(256) void k_conv1(const float* __restrict__ x,
        const unsigned short* __restrict__ W5BF,
        unsigned short* __restrict__ Y1T, unsigned short* __restrict__ Y2C,
        float* __restrict__ STATS1) {
    __shared__ unsigned short xt[64][264];
    __shared__ float lds_part[4][64];
    int lt = blockIdx.x, b = blockIdx.y;
    int l0 = lt * 64;
    int t = threadIdx.x;
    {   // stage: lane j = l offset (coalesced), cg = channel quarter
        int j = t & 63, cg = t >> 6;
        int ls = l0 - 1 + j;
        bool ok = (ls >= 0) && (ls < L);
        const float* xs = x + (size_t)(b * C + cg * 64) * L + ls;
        unsigned short* row = &xt[j][cg * 64];
#pragma unroll 8
        for (int cc = 0; cc < 64; ++cc) {
            float v = ok ? xs[(size_t)cc * L] : 0.f;
            row[cc] = f2bf(v);
        }
    }
    __syncthreads();
    int w = t >> 6, lane = t & 63, n = lane & 15, quad = lane >> 4;
    bshort8 wf[2][8];
#pragma unroll
    for (int oi = 0; oi < 2; ++oi)
#pragma unroll
        for (int kt = 0; kt < 8; ++kt)
            wf[oi][kt] = *(const bshort8*)(W5BF + (size_t)((w * 2 + oi) * 16 + n) * C + kt * 32 + quad * 8);
    f32x4 acc[2][4];
#pragma unroll
    for (int oi = 0; oi < 2; ++oi)
#pragma unroll
        for (int sub = 0; sub < 4; ++sub) acc[oi][sub] = (f32x4){0.f, 0.f, 0.f, 0.f};
#pragma unroll
    for (int sub = 0; sub < 4; ++sub) {
        int lloc = sub * 16 + n;
#pragma unroll
        for (int kt = 0; kt < 8; ++kt) {
            bshort8 xb = *(const bshort8*)(&xt[lloc][kt * 32 + quad * 8]);
            acc[0][sub] = __builtin_amdgcn_mfma_f32_16x16x32_bf16(wf[0][kt], xb, acc[0][sub], 0, 0, 0);
            acc[1][sub] = __builtin_amdgcn_mfma_f32_16x16x32_bf16(wf[1][kt], xb, acc[1][sub], 0, 0, 0);
        }
    }
    if (w < 2) {
#pragma unroll
        for (int sub = 0; sub < 4; ++sub) {
            int lp = l0 + sub * 16 + n;
#pragma unroll
            for (int oi = 0; oi < 2; ++oi) {
                int ot = w * 2 + oi;
                uint2 pv;
                pv.x = pk2(acc[oi][sub][0], acc[oi][sub][1]);
                pv.y = pk2(acc[oi][sub][2], acc[oi][sub][3]);
                *(uint2*)(Y1T + ((size_t)(b * LP + lp)) * IC + ot * 16 + quad * 4) = pv;
            }
        }
    } else {
#pragma unroll
        for (int oi = 0; oi < 2; ++oi) {
            int ot = (w - 2) * 2 + oi;
#pragma unroll
            for (int r = 0; r < 4; ++r) {
                int o = ot * 16 + quad * 4 + r;
                unsigned short* dst = Y2C + ((size_t)(b * IC + o)) * LP + l0;
#pragma unroll
                for (int sub = 0; sub < 4; ++sub)
                    dst[sub * 16 + n] = f2bf(acc[oi][sub][r]);
            }
        }
    }
#pragma unroll
    for (int oi = 0; oi < 2; ++oi)
#pragma unroll
        for (int r = 0; r < 4; ++r) {
            float s = 0.f, q = 0.f;
#pragma unroll
            for (int sub = 0; sub < 4; ++sub) {
                float v = acc[oi][sub][r];
                s += v; q += v * v;
            }
#pragma unroll
            for (int msk = 1; msk < 16; msk <<= 1) {
                s += __shfl_xor(s, msk, 64);
                q += __shfl_xor(q, msk, 64);
            }
            if (n == 0) {
                int ci = oi * 16 + quad * 4 + r;
                lds_part[w][ci * 2] = s;
                lds_part[w][ci * 2 + 1] = q;
            }
        }
    __syncthreads();
    {
        int ch = t >> 1, wsrc = ch >> 5;
        int idx = ((ch & 31) << 1) | (t & 1);
        atomicAdd(&STATS1[(blockIdx.x & 3) * 256 + t], lds_part[wsrc][idx]);
    }
}

// ================= fuse1: qkv (256 blocks) | gram (32 blocks) =================
__device__ void role_qkv(char* dynsm, int lt, int b,
        const unsigned short* __restrict__ Y1T, const float* __restrict__ STATS1,
        const float* __restrict__ g5a, const float* __restrict__ b5a,
        const unsigned short* __restrict__ WQKV, const float* __restrict__ BQKV,
        unsigned short* __restrict__ QT, unsigned short* __restrict__ KT,
        unsigned short* __restrict__ VB) {
    float* cA = (float*)dynsm;
    float* cB = cA + 64;
    load_coef(STATS1, g5a, b5a, 0, 64, cA, cB);
    __syncthreads();
    int t = threadIdx.x;
    int w = t >> 6, lane = t & 63, n = lane & 15, quad = lane >> 4;
    int lrow = lt * 64 + w * 16 + n;
    bshort8 fb[2];
#pragma unroll
    for (int kt = 0; kt < 2; ++kt) {
        bshort8 raw = *(const bshort8*)(Y1T + ((size_t)(b * LP + lrow)) * IC + kt * 32 + quad * 8);
        bshort8 f;
#pragma unroll
        for (int j = 0; j < 8; ++j) {
            int c = kt * 32 + quad * 8 + j;
            float v = fmaxf(fmaf(cA[c], bf2f((unsigned short)raw[j]), cB[c]), 0.f);
            ((unsigned short*)&f)[j] = f2bf(v);
        }
        fb[kt] = f;
    }
    f32x4 acc[5];
#pragma unroll
    for (int ot = 0; ot < 5; ++ot) {
        f32x4 a = {0.f, 0.f, 0.f, 0.f};
#pragma unroll
        for (int kt = 0; kt < 2; ++kt) {
            bshort8 wf = *(const bshort8*)(WQKV + (size_t)(ot * 16 + n) * IC + kt * 32 + quad * 8);
            a = __builtin_amdgcn_mfma_f32_16x16x32_bf16(wf, fb[kt], a, 0, 0, 0);
        }
        acc[ot] = a;
    }
#pragma unroll
    for (int ot = 0; ot < 5; ++ot)
#pragma unroll
        for (int r = 0; r < 4; ++r) {
            int o = ot * 16 + quad * 4 + r;
            unsigned short bv16 = f2bf(acc[ot][r] + BQKV[o]);
            if (ot == 0) {
                if (o < 8) QT[((size_t)(b * LP + lrow)) * 8 + o] = bv16;
                else KT[((size_t)(b * LP + lrow)) * 8 + (o - 8)] = bv16;
            } else {
                VB[((size_t)(b * IC + (o - 16))) * LP + lrow] = bv16;
            }
        }
}

__device__ void role_gram(char* dynsm, int blk, int b,
        const unsigned short* __restrict__ Y2C, const float* __restrict__ STATS1,
        const float* __restrict__ g5c, const float* __restrict__ b5c,
        float* __restrict__ EPART) {
    float* cA = (float*)dynsm;
    float* cB = cA + 64;
    load_coef(STATS1, g5c, b5c, 64, 64, cA, cB);
    __syncthreads();
    int t = threadIdx.x;
    int w = t >> 6, lane = t & 63, n = lane & 15, quad = lane >> 4;
    f32x4 acc[4][4];
#pragma unroll
    for (int ti = 0; ti < 4; ++ti)
#pragma unroll
        for (int tj = 0; tj < 4; ++tj) acc[ti][tj] = (f32x4){0.f, 0.f, 0.f, 0.f};
    for (int chunk = 0; chunk < 4; ++chunk) {
        int lb = (blk * 4 + w) * 128 + chunk * 32 + quad * 8;
        bshort8 frag[4];
#pragma unroll
        for (int g = 0; g < 4; ++g) {
            int c = g * 16 + n;
            bshort8 raw = *(const bshort8*)(Y2C + ((size_t)(b * IC + c)) * LP + lb);
            bshort8 f;
            float A = cA[c], Bc = cB[c];
#pragma unroll
            for (int j = 0; j < 8; ++j)
                ((unsigned short*)&f)[j] = f2bf(fmaxf(fmaf(A, bf2f((unsigned short)raw[j]), Bc), 0.f));
            frag[g] = f;
        }
#pragma unroll
        for (int ti = 0; ti < 4; ++ti)
#pragma unroll
            for (int tj = 0; tj < 4; ++tj)
                acc[ti][tj] = __builtin_amdgcn_mfma_f32_16x16x32_bf16(frag[ti], frag[tj], acc[ti][tj], 0, 0, 0);
    }
    float* ep = EPART + ((size_t)(b * 16 + blk * 4 + w)) * 4096;
#pragma unroll
    for (int ti = 0; ti < 4; ++ti)
#pragma unroll
        for (int tj = 0; tj < 4; ++tj)
#pragma unroll
            for (int r = 0; r < 4; ++r)
                ep[(ti * 16 + quad * 4 + r) * 64 + tj * 16 + n] = acc[ti][tj][r];
}

__global__ __launch_bounds__(256) void k_fuse1(
        const unsigned short* __restrict__ Y1T, const unsigned short* __restrict__ Y2C,
        const float* __restrict__ STATS1,
        const float* __restrict__ g5a, const float* __restrict__ b5a,
        const float* __restrict__ g5c, const float* __restrict__ b5c,
        const unsigned short* __restrict__ WQKV, const float* __restrict__ BQKV,
        unsigned short* __restrict__ QT, unsigned short* __restrict__ KT,
        unsigned short* __restrict__ VB, float* __restrict__ EPART) {
    extern __shared__ char dynsm[];
    int idx = blockIdx.x;
    if (idx < 256) role_qkv(dynsm, idx & 31, idx >> 5, Y1T, STATS1, g5a, b5a,
                            WQKV, BQKV, QT, KT, VB);
    else { int g = idx - 256; role_gram(dynsm, g & 3, g >> 2, Y2C, STATS1, g5c, b5c, EPART); }
}

// ===== fuse2: pam (1024 blocks, V double-buffered) | cam_softmax (8) =====
__device__ void role_pam(char* dynsm, int qt, int ks, int b,
        const unsigned short* __restrict__ qT, const unsigned short* __restrict__ kT,
        const unsigned short* __restrict__ vb,
        unsigned short* __restrict__ OPART, float* __restrict__ LPART) {
    unsigned short* vs0 = (unsigned short*)dynsm;     // [64][72]
    unsigned short* vs1 = vs0 + 4608;                 // [64][72]
    unsigned short* ps  = vs1 + 4608;                 // 4 x [16][72]
    float* os = (float*)dynsm;                        // [64][65] aliased after loop
    int l0 = qt * 64;
    int tid = threadIdx.x;
    int wq = tid >> 6, lane = tid & 63, n = lane & 15, quad = lane >> 4;
    int srow = tid >> 2, schn = tid & 3;
    bshort8 qa = {};
    if (quad == 0)
        qa = *(const bshort8*)(qT + ((size_t)(b * LP + l0 + wq * 16 + n)) * 8);
    f32x4 acc[4];
#pragma unroll
    for (int s = 0; s < 4; ++s) acc[s] = (f32x4){0.f, 0.f, 0.f, 0.f};
    float li[4] = {0.f, 0.f, 0.f, 0.f};
    unsigned short* pw = ps + wq * 16 * 72;

    {   // prologue: stage tile 0
        const unsigned short* src = vb + ((size_t)(b * IC + srow)) * LP + ks * 512 + schn * 16;
        unsigned short* d = vs0 + srow * 72 + schn * 16;
        *(bshort8*)d = *(const bshort8*)src;
        *(bshort8*)(d + 8) = *(const bshort8*)(src + 8);
    }
    __syncthreads();
    for (int it = 0; it < 8; ++it) {
        unsigned short* cur = (it & 1) ? vs1 : vs0;
        unsigned short* nxt = (it & 1) ? vs0 : vs1;
        if (it < 7) {   // prefetch next V tile into the other buffer
            const unsigned short* src = vb + ((size_t)(b * IC + srow)) * LP + ks * 512 + (it + 1) * 64 + schn * 16;
            unsigned short* d = nxt + srow * 72 + schn * 16;
            *(bshort8*)d = *(const bshort8*)src;
            *(bshort8*)(d + 8) = *(const bshort8*)(src + 8);
        }
        int m0 = ks * 512 + it * 64;
        bshort8 kb[4];
#pragma unroll
        for (int s = 0; s < 4; ++s) kb[s] = (bshort8){};
        if (quad == 0) {
#pragma unroll
            for (int s = 0; s < 4; ++s)
                kb[s] = *(const bshort8*)(kT + ((size_t)(b * LP + m0 + s * 16 + n)) * 8);
        }
        f32x4 sc[4];
#pragma unroll
        for (int s = 0; s < 4; ++s)
            sc[s] = __builtin_amdgcn_mfma_f32_16x16x32_bf16(qa, kb[s],
                        (f32x4){0.f, 0.f, 0.f, 0.f}, 0, 0, 0);
#pragma unroll
        for (int s = 0; s < 4; ++s)
#pragma unroll
            for (int r = 0; r < 4; ++r) {
                float p = __expf(sc[s][r]);
                li[r] += p;
                pw[(quad * 4 + r) * 72 + s * 16 + n] = f2bf(p);
            }
#pragma unroll
        for (int step = 0; step < 2; ++step) {
            bshort8 pa = *(const bshort8*)(pw + n * 72 + step * 32 + quad * 8);
#pragma unroll
            for (int s = 0; s < 4; ++s) {
                bshort8 vf = *(const bshort8*)(cur + (s * 16 + n) * 72 + step * 32 + quad * 8);
                acc[s] = __builtin_amdgcn_mfma_f32_16x16x32_bf16(pa, vf, acc[s], 0, 0, 0);
            }
        }
        __syncthreads();   // prefetch done + all reads of cur done
    }
#pragma unroll
    for (int s = 0; s < 4; ++s)
#pragma unroll
        for (int r = 0; r < 4; ++r)
            os[(s * 16 + n) * 65 + wq * 16 + quad * 4 + r] = acc[s][r];
    size_t lbase = ((size_t)((b * 32 + qt) * 4 + ks)) * 64;
#pragma unroll
    for (int r = 0; r < 4; ++r) {
        float s_ = li[r];
#pragma unroll
        for (int msk = 1; msk < 16; msk <<= 1) s_ += __shfl_xor(s_, msk, 64);
        if (n == 0) LPART[lbase + wq * 16 + quad * 4 + r] = s_;
    }
    __syncthreads();
    size_t ob = ((size_t)((b * 32 + qt) * 4 + ks)) * 4096;
    int c = tid >> 2, qc = tid & 3;
    unsigned int* od = (unsigned int*)(OPART + ob + c * 64 + qc * 16);
#pragma unroll
    for (int i = 0; i < 8; ++i)
        od[i] = pk2(os[c * 65 + qc * 16 + 2 * i], os[c * 65 + qc * 16 + 2 * i + 1]);
}

__device__ void role_cam_softmax(char* dynsm, int b,
        const float* __restrict__ EPART, float* __restrict__ attn) {
    float* e = (float*)dynsm;
    int t = threadIdx.x;
    for (int idx = t; idx < 4096; idx += 256) {
        float s = 0.f;
        for (int ch = 0; ch < 16; ++ch) s += EPART[((size_t)(b * 16 + ch)) * 4096 + idx];
        e[idx] = s;
    }
    __syncthreads();
    if (t < 64) {
        float mn = INFINITY;
        for (int d = 0; d < 64; ++d) mn = fminf(mn, e[t * 64 + d]);
        float s = 0.f;
        float* a = attn + (size_t)b * 4096 + t * 64;
        for (int d = 0; d < 64; ++d) { float p = __expf(mn - e[t * 64 + d]); a[d] = p; s += p; }
        float inv = 1.f / s;
        for (int d = 0; d < 64; ++d) a[d] *= inv;
    }
}

__global__ __launch_bounds__(256) void k_fuse2(
        const unsigned short* __restrict__ QT, const unsigned short* __restrict__ KT,
        const unsigned short* __restrict__ VB,
        unsigned short* __restrict__ OPART, float* __restrict__ LPART,
        const float* __restrict__ EPART, float* __restrict__ ATTN) {
    extern __shared__ char dynsm[];
    int idx = blockIdx.x;
    if (idx < 1024) role_pam(dynsm, idx & 31, (idx >> 5) & 3, idx >> 7, QT, KT, VB, OPART, LPART);
    else role_cam_softmax(dynsm, idx - 1024, EPART, ATTN);
}

// ====== fuse3c: {pam_combine|cam_apply} + conv3 from LDS tile (512 blocks) ======
// shared conv3 tail: tile[66][72] rows = l0-1 .. l0+64
__device__ __forceinline__ void conv3_from_tile(const unsigned short* tile,
        const unsigned short* __restrict__ WT, unsigned short* __restrict__ dst,
        int b, int l0, float* lds_part, float* __restrict__ STATS2,
        int og, int blockx) {
    int t = threadIdx.x;
    int w = t >> 6, lane = t & 63, n = lane & 15, quad = lane >> 4;
    int lrow = l0 + w * 16 + n;
    f32x4 acc[4];
#pragma unroll
    for (int ot = 0; ot < 4; ++ot) acc[ot] = (f32x4){0.f, 0.f, 0.f, 0.f};
#pragma unroll
    for (int t3 = 0; t3 < 3; ++t3) {
        int trow = w * 16 + n + t3;   // tile row (= l + t3 - 1 relative, +1 bias)
        bshort8 fb0 = *(const bshort8*)(tile + trow * 72 + quad * 8);
        bshort8 fb1 = *(const bshort8*)(tile + trow * 72 + 32 + quad * 8);
#pragma unroll
        for (int ot = 0; ot < 4; ++ot) {
            bshort8 w0 = *(const bshort8*)(WT + ((size_t)(t3 * 64 + ot * 16 + n)) * IC + quad * 8);
            bshort8 w1 = *(const bshort8*)(WT + ((size_t)(t3 * 64 + ot * 16 + n)) * IC + 32 + quad * 8);
            acc[ot] = __builtin_amdgcn_mfma_f32_16x16x32_bf16(w0, fb0, acc[ot], 0, 0, 0);
            acc[ot] = __builtin_amdgcn_mfma_f32_16x16x32_bf16(w1, fb1, acc[ot], 0, 0, 0);
        }
    }
#pragma unroll
    for (int ot = 0; ot < 4; ++ot) {
        uint2 pv;
        pv.x = pk2(acc[ot][0], acc[ot][1]);
        pv.y = pk2(acc[ot][2], acc[ot][3]);
        *(uint2*)(dst + ((size_t)(b * LP + lrow)) * IC + ot * 16 + quad * 4) = pv;
    }
#pragma unroll
    for (int ot = 0; ot < 4; ++ot)
#pragma unroll
        for (int r = 0; r < 4; ++r) {
            float s = acc[ot][r], q = s * s;
#pragma unroll
            for (int msk = 1; msk < 16; msk <<= 1) {
                s += __shfl_xor(s, msk, 64);
                q += __shfl_xor(q, msk, 64);
            }
            if (n == 0) {
                int cch = ot * 16 + quad * 4 + r;
                lds_part[w * 128 + cch * 2] = s;
                lds_part[w * 128 + cch * 2 + 1] = q;
            }
        }
    __syncthreads();
    if (t < 128) {
        float s = lds_part[t] + lds_part[128 + t] + lds_part[256 + t] + lds_part[384 + t];
        atomicAdd(&STATS2[(blockx & 3) * 256 + og * 128 + t], s);
    }
}

__device__ void role_pam_c3(char* dynsm, int qt, int b,
        const unsigned short* __restrict__ OPART, const float* __restrict__ LPART,
        const unsigned short* __restrict__ Y1T, const float* __restrict__ STATS1,
        const float* __restrict__ g5a, const float* __restrict__ b5a,
        const float* __restrict__ gamma, const unsigned short* __restrict__ WT,
        unsigned short* __restrict__ Y51T, float* __restrict__ STATS2) {
    float* dn = (float*)dynsm;                         // 64
    float* cA = dn + 64; float* cB = cA + 64;
    unsigned short* tile = (unsigned short*)(cB + 64); // [66][72]
    float* lds_part = (float*)(tile + 4752);           // 512 floats
    int l0 = qt * 64;
    int t = threadIdx.x;
    load_coef(STATS1, g5a, b5a, 0, 64, cA, cB);
    if (t < 64) {
        size_t lbase = ((size_t)((b * 32 + qt) * 4)) * 64;
        dn[t] = LPART[lbase + t] + LPART[lbase + 64 + t] +
                LPART[lbase + 128 + t] + LPART[lbase + 192 + t];
    }
    __syncthreads();
    float gm = gamma[0];
    {   // interior rows 0..63 -> tile rows 1..64
        int c = t >> 2, qc = t & 3;
        float O[16];
#pragma unroll
        for (int i = 0; i < 16; ++i) O[i] = 0.f;
        size_t ob = ((size_t)((b * 32 + qt) * 4)) * 4096 + c * 64 + qc * 16;
#pragma unroll
        for (int s = 0; s < 4; ++s) {
            bshort8 p0 = *(const bshort8*)(OPART + ob + (size_t)s * 4096);
            bshort8 p1 = *(const bshort8*)(OPART + ob + (size_t)s * 4096 + 8);
#pragma unroll
            for (int i = 0; i < 8; ++i) {
                O[i]     += bf2f((unsigned short)p0[i]);
                O[8 + i] += bf2f((unsigned short)p1[i]);
            }
        }
#pragma unroll
        for (int i = 0; i < 16; ++i) {
            int q = qc * 16 + i;
            unsigned short raw = Y1T[((size_t)(b * LP + l0 + q)) * IC + c];
            float f1v = fmaxf(fmaf(cA[c], bf2f(raw), cB[c]), 0.f);
            tile[(1 + q) * 72 + c] = f2bf(fmaf(gm, O[i] / dn[q], f1v));
        }
    }
    if (t < 128) {   // halo rows
        int row = (t & 1) ? 65 : 0;
        int ch = t >> 1;
        int l = l0 - 1 + row;
        float val = 0.f;
        if (l >= 0 && l < LP) {
            int qh = l >> 6, lih = l & 63;
            size_t lb2 = ((size_t)((b * 32 + qh) * 4)) * 64;
            float dnh = LPART[lb2 + lih] + LPART[lb2 + 64 + lih] +
                        LPART[lb2 + 128 + lih] + LPART[lb2 + 192 + lih];
            size_t ob2 = ((size_t)((b * 32 + qh) * 4)) * 4096 + ch * 64 + lih;
            float Oh = bf2f(OPART[ob2]) + bf2f(OPART[ob2 + 4096]) +
                       bf2f(OPART[ob2 + 8192]) + bf2f(OPART[ob2 + 12288]);
            float f1v = fmaxf(fmaf(cA[ch], bf2f(Y1T[((size_t)(b * LP + l)) * IC + ch]), cB[ch]), 0.f);
            val = fmaf(gm, Oh / dnh, f1v);
        }
        tile[row * 72 + ch] = f2bf(val);
    }
    __syncthreads();
    conv3_from_tile(tile, WT, Y51T, b, l0, lds_part, STATS2, 0, qt);
}

__device__ void role_cam_c3(char* dynsm, int lt, int b,
        const float* __restrict__ attn, const unsigned short* __restrict__ Y2C,
        const float* __restrict__ STATS1,
        const float* __restrict__ g5c, const float* __restrict__ b5c,
        const float* __restrict__ gamma, const unsigned short* __restrict__ WT,
        unsigned short* __restrict__ Y52T, float* __restrict__ STATS2) {
    float* as = (float*)dynsm;                         // 4096
    float* cA = as + 4096; float* cB = cA + 64;
    unsigned short* tile = (unsigned short*)(cB + 64); // [66][72]
    float* lds_part = (float*)(tile + 4752);
    int l0 = lt * 64;
    int t = threadIdx.x;
    load_coef(STATS1, g5c, b5c, 64, 64, cA, cB);
    for (int i = t; i < 4096; i += 256) as[i] = attn[(size_t)b * 4096 + i];
    __syncthreads();
    float gm = gamma[0];
    {   // interior: lq row, cg = 16-channel group
        int lq = t & 63, cg = t >> 6;
        const unsigned short* fb = Y2C + (size_t)b * IC * LP + l0 + lq;
        float acc[16];
#pragma unroll
        for (int i = 0; i < 16; ++i) acc[i] = 0.f;
        for (int d4 = 0; d4 < 16; ++d4) {
            float fv[4];
#pragma unroll
            for (int i = 0; i < 4; ++i) {
                int d = 4 * d4 + i;
                fv[i] = fmaxf(fmaf(cA[d], bf2f(fb[(size_t)d * LP]), cB[d]), 0.f);
            }
#pragma unroll
            for (int cc = 0; cc < 16; ++cc) {
                const float4 a4 = *reinterpret_cast<const float4*>(as + (cg * 16 + cc) * 64 + d4 * 4);
                acc[cc] += a4.x * fv[0] + a4.y * fv[1] + a4.z * fv[2] + a4.w * fv[3];
            }
        }
#pragma unroll
        for (int cc = 0; cc < 16; ++cc) {
            int c = cg * 16 + cc;
            float res = fmaxf(fmaf(cA[c], bf2f(fb[(size_t)c * LP]), cB[c]), 0.f);
            tile[(1 + lq) * 72 + c] = f2bf(fmaf(gm, acc[cc], res));
        }
    }
    if (t < 128) {   // halo rows
        int row = (t & 1) ? 65 : 0;
        int ch = t >> 1;
        int l = l0 - 1 + row;
        float val = 0.f;
        if (l >= 0 && l < LP) {
            const unsigned short* fb = Y2C + (size_t)b * IC * LP + l;
            float a = 0.f;
            for (int d = 0; d < 64; ++d) {
                float fv = fmaxf(fmaf(cA[d], bf2f(fb[(size_t)d * LP]), cB[d]), 0.f);
                a = fmaf(as[ch * 64 + d], fv, a);
            }
            float res = fmaxf(fmaf(cA[ch], bf2f(fb[(size_t)ch * LP]), cB[ch]), 0.f);
            val = fmaf(gm, a, res);
        }
        tile[row * 72 + ch] = f2bf(val);
    }
    __syncthreads();
    conv3_from_tile(tile, WT, Y52T, b, l0, lds_part, STATS2, 1, lt);
}

__global__ __launch_bounds__(256) void k_fuse3c(
        const unsigned short* __restrict__ OPART, const float* __restrict__ LPART,
        const unsigned short* __restrict__ Y1T, const unsigned short* __restrict__ Y2C,
        const float* __restrict__ STATS1,
        const float* __restrict__ g5a, const float* __restrict__ b5a,
        const float* __restrict__ g5c, const float* __restrict__ b5c,
        const float* __restrict__ gpam, const float* __restrict__ gcam,
        const float* __restrict__ ATTN, const unsigned short* __restrict__ WTall,
        unsigned short* __restrict__ Y51T, unsigned short* __restrict__ Y52T,
        float* __restrict__ STATS2) {
    extern __shared__ char dynsm[];
    int idx = blockIdx.x;
    if (idx < 256) role_pam_c3(dynsm, idx & 31, idx >> 5, OPART, LPART, Y1T,
                               STATS1, g5a, b5a, gpam, WTall, Y51T, STATS2);
    else { int g = idx - 256; role_cam_c3(dynsm, g & 31, g >> 5, ATTN, Y2C,
                                          STATS1, g5c, b5c, gcam, WTall + 12288,
                                          Y52T, STATS2); }
}

// ---- final conv1x1 pair + fused sasc projection (out pre-initialized to b8) ----
__global__ __launch_bounds__(256) void k_final(const unsigned short* __restrict__ Y51T,
        const unsigned short* __restrict__ Y52T, const float* __restrict__ STATS2,
        const float* __restrict__ g51, const float* __restrict__ b51,
        const float* __restrict__ g52, const float* __restrict__ b52,
        const unsigned short* __restrict__ W67,
        const float* __restrict__ b6, const float* __restrict__ b7,
        const float* __restrict__ W8,
        float* __restrict__ out_sa, float* __restrict__ out_sc,
        float* __restrict__ out_sasc) {
    __shared__ float cA[128], cB[128];
    __shared__ float fsw[4][64];
    __shared__ float chsum[64];
    int lt = blockIdx.x, og = blockIdx.y, b = blockIdx.z;
    int t = threadIdx.x;
    if (t < 128) {
        float s = STATS2[t * 2] + STATS2[256 + t * 2] + STATS2[512 + t * 2] + STATS2[768 + t * 2];
        float q = STATS2[t * 2 + 1] + STATS2[256 + t * 2 + 1] + STATS2[512 + t * 2 + 1] + STATS2[768 + t * 2 + 1];
        float mu = s * INVN, var = q * INVN - mu * mu;
        float gv = t < 64 ? g51[t] : g52[t - 64];
        float bv = t < 64 ? b51[t] : b52[t - 64];
        float A = gv * rsqrtf(var + BN_EPS);
        cA[t] = A; cB[t] = bv - mu * A;
    }
    __syncthreads();
    int w = t >> 6, lane = t & 63, n = lane & 15, quad = lane >> 4;
    int lrow = lt * 64 + w * 16 + n;
    float fs_lane[16];
    bshort8 ba[2], bb[2];
#pragma unroll
    for (int kt = 0; kt < 2; ++kt) {
        bshort8 ra = *(const bshort8*)(Y51T + ((size_t)(b * LP + lrow)) * IC + kt * 32 + quad * 8);
        bshort8 rb = *(const bshort8*)(Y52T + ((size_t)(b * LP + lrow)) * IC + kt * 32 + quad * 8);
        bshort8 fa, fb;
#pragma unroll
        for (int j = 0; j < 8; ++j) {
            int c = kt * 32 + quad * 8 + j;
            float v1 = fmaxf(fmaf(cA[c], bf2f((unsigned short)ra[j]), cB[c]), 0.f);
            float v2 = fmaxf(fmaf(cA[64 + c], bf2f((unsigned short)rb[j]), cB[64 + c]), 0.f);
            ((unsigned short*)&fa)[j] = f2bf(v1);
            ((unsigned short*)&fb)[j] = f2bf(v2);
            fs_lane[kt * 8 + j] = v1 + v2;
        }
        ba[kt] = fa; bb[kt] = fb;
    }
    f32x4 accA[4], accB[4];
#pragma unroll
    for (int ot = 0; ot < 4; ++ot) {
        accA[ot] = (f32x4){0.f, 0.f, 0.f, 0.f};
        accB[ot] = (f32x4){0.f, 0.f, 0.f, 0.f};
    }
#pragma unroll
    for (int ot = 0; ot < 4; ++ot)
#pragma unroll
        for (int kt = 0; kt < 2; ++kt) {
            bshort8 wa = *(const bshort8*)(W67 + (size_t)(og * 64 + ot * 16 + n) * IC + kt * 32 + quad * 8);
            bshort8 wb = *(const bshort8*)(W67 + 8192 + (size_t)(og * 64 + ot * 16 + n) * IC + kt * 32 + quad * 8);
            accA[ot] = __builtin_amdgcn_mfma_f32_16x16x32_bf16(wa, ba[kt], accA[ot], 0, 0, 0);
            accB[ot] = __builtin_amdgcn_mfma_f32_16x16x32_bf16(wb, bb[kt], accB[ot], 0, 0, 0);
        }
#pragma unroll
    for (int ot = 0; ot < 4; ++ot)
#pragma unroll
        for (int r = 0; r < 4; ++r) {
            int o = og * 64 + ot * 16 + quad * 4 + r;
            out_sa[((size_t)(b * OC + o)) * LP + lrow] = accA[ot][r] + b6[o];
            out_sc[((size_t)(b * OC + o)) * LP + lrow] = accB[ot][r] + b7[o];
        }
    if (og == 0) {
#pragma unroll
        for (int i = 0; i < 16; ++i) {
            float s = fs_lane[i];
#pragma unroll
            for (int msk = 1; msk < 16; msk <<= 1) s += __shfl_xor(s, msk, 64);
            if (n == 0) {
                int c = (i >> 3) * 32 + quad * 8 + (i & 7);
                fsw[w][c] = s;
            }
        }
        __syncthreads();
        if (t < 64) chsum[t] = fsw[0][t] + fsw[1][t] + fsw[2][t] + fsw[3][t];
        __syncthreads();
        if (t < 128) {
            float s = 0.f;
            for (int c = 0; c < 64; ++c) s = fmaf(W8[t * 64 + c], chsum[c], s);
            atomicAdd(&out_sasc[b * OC + t], s * (1.f / (float)LP));
        }
    }
}

extern "C" void kernel_launch(void* const* d_in, const int* in_sizes, int n_in,
                              void* d_out, int out_size, void* d_ws, size_t ws_size,
                              hipStream_t stream) {
    (void)in_sizes; (void)n_in; (void)out_size; (void)ws_size;
    const float* x    = (const float*)d_in[0];
    const float* W5a  = (const float*)d_in[1];
    const float* g5a  = (const float*)d_in[2];
    const float* b5a  = (const float*)d_in[3];
    const float* W5c  = (const float*)d_in[4];
    const float* g5c  = (const float*)d_in[5];
    const float* b5c  = (const float*)d_in[6];
    const float* Wq   = (const float*)d_in[7];
    const float* bq   = (const float*)d_in[8];
    const float* Wk   = (const float*)d_in[9];
    const float* bk   = (const float*)d_in[10];
    const float* Wv   = (const float*)d_in[11];
    const float* bv   = (const float*)d_in[12];
    const float* gpam = (const float*)d_in[13];
    const float* gcam = (const float*)d_in[14];
    const float* W51  = (const float*)d_in[15];
    const float* g51  = (const float*)d_in[16];
    const float* b51  = (const float*)d_in[17];
    const float* W52  = (const float*)d_in[18];
    const float* g52  = (const float*)d_in[19];
    const float* b52  = (const float*)d_in[20];
    const float* W6   = (const float*)d_in[21];
    const float* b6   = (const float*)d_in[22];
    const float* W7   = (const float*)d_in[23];
    const float* b7   = (const float*)d_in[24];
    const float* W8   = (const float*)d_in[25];
    const float* b8   = (const float*)d_in[26];

    float* ws = (float*)d_ws;
    float* out = (float*)d_out;
    unsigned short* Y1T  = (unsigned short*)(ws + OFF_Y1T);
    unsigned short* Y2C  = (unsigned short*)(ws + OFF_Y2C);
    unsigned short* Y51T = (unsigned short*)(ws + OFF_Y51T);
    unsigned short* Y52T = (unsigned short*)(ws + OFF_Y52T);
    unsigned short* VB   = (unsigned short*)(ws + OFF_VB);
    unsigned short* QT   = (unsigned short*)(ws + OFF_QT);
    unsigned short* KT   = (unsigned short*)(ws + OFF_KT);
    float* LPART  = ws + OFF_LPART;
    float* EPART  = ws + OFF_EPART;
    float* ATTN   = ws + OFF_ATTN;
    float* STATS1 = ws + OFF_STATS1;
    float* STATS2 = ws + OFF_STATS2;
    unsigned short* W5BF = (unsigned short*)(ws + OFF_W5BF);
    unsigned short* W67  = (unsigned short*)(ws + OFF_W67);
    unsigned short* WT   = (unsigned short*)(ws + OFF_WT);
    unsigned short* WQKV = (unsigned short*)(ws + OFF_WQKV);
    float* BQKV = ws + OFF_BQKV;

    float* out_sa = out + B * OC;
    float* out_sc = out + B * OC + (size_t)B * OC * LP;
    unsigned short* OPART = (unsigned short*)out_sa;  // scratch, overwritten by k_final

    k_wprep<<<321, 256, 0, stream>>>(W5a, W5c, W6, W7, W51, W52, Wq, Wk, Wv,
                                     bq, bk, bv, b8, W5BF, W67, WT, WQKV, BQKV,
                                     STATS1, STATS2, out);
    k_conv1<<<dim3(32, B), 256, 0, stream>>>(x, W5BF, Y1T, Y2C, STATS1);
    k_fuse1<<<288, 256, 512, stream>>>(Y1T, Y2C, STATS1, g5a, b5a, g5c, b5c,
                                       WQKV, BQKV, QT, KT, VB, EPART);
    k_fuse2<<<1032, 256, 27648, stream>>>(QT, KT, VB, OPART, LPART, EPART, ATTN);
    k_fuse3c<<<512, 256, 28448, stream>>>(OPART, LPART, Y1T, Y2C, STATS1,
                                          g5a, b5a, g5c, b5c, gpam, gcam, ATTN,
                                          WT, Y51T, Y52T, STATS2);
    k_final<<<dim3(32, 2, B), 256, 0, stream>>>(Y51T, Y52T, STATS2, g51, b51, g52, b52,
                                                W67, b6, b7, W8, out_sa, out_sc, out);
}

// Round 10
// 214.578 us; speedup vs baseline: 1.2778x; 1.0015x over previous
//
#include <hip/hip_runtime.h>
#include <math.h>

#define B 8
#define C 256
#define L 2046
#define LP 2048
#define IC 64
#define OC 128
#define BN_EPS 1e-5f
#define INVN (1.f / 16384.f)   // 1/(B*LP)

// ws offsets (float units)
#define OFF_Y1T    0u          // conv1 out (pre-BN) bf16 [b][l][64]
#define OFF_Y2C    524288u     // conv1 out (pre-BN) bf16 [b][64][l]
#define OFF_Y51T   2097152u    // conv3 out (pre-BN) bf16 [b][l][64]
#define OFF_Y52T   2621440u
#define OFF_VB     3145728u    // v bf16 [b][64][l]
#define OFF_QT     3670016u    // q bf16 [b][l][8]
#define OFF_KT     3735552u
#define OFF_LPART  3801088u    // pam denominators [b][32][4][64]
#define OFF_EPART  3866624u    // CAM gram partials [b][16][64][64]
#define OFF_ATTN   4390912u
#define OFF_STATS1 4423680u    // [4 copies][128ch][2] atomic sum/sumsq
#define OFF_STATS2 4424704u
#define OFF_W5BF   4425728u    // bf16 [128][256]
#define OFF_W67    4442112u    // bf16 [2][128][64]
#define OFF_WT     4450304u    // bf16 [2][3][64][64]
#define OFF_WQKV   4462592u    // bf16 [80][64]
#define OFF_BQKV   4465152u    // fp32 [80]

typedef __attribute__((ext_vector_type(8))) short bshort8;
typedef __attribute__((ext_vector_type(4))) float f32x4;

// fast bf16 round-half-up (differs from RTNE only on exact ties)
__device__ __forceinline__ unsigned short f2bf(float f) {
    union { float f; unsigned int u; } v; v.f = f;
    return (unsigned short)((v.u + 0x8000u) >> 16);
}
__device__ __forceinline__ float bf2f(unsigned short u) {
    union { unsigned int i; float f; } v; v.i = ((unsigned int)u) << 16;
    return v.f;
}
__device__ __forceinline__ unsigned int pk2(float a, float b) {
    union { float f; unsigned int u; } va, vb; va.f = a; vb.f = b;
    return __builtin_amdgcn_perm(vb.u + 0x8000u, va.u + 0x8000u, 0x07060302u);
}

// BN affine coefs from 4-copy atomic stats
__device__ __forceinline__ void load_coef(const float* __restrict__ STATS,
        const float* __restrict__ g, const float* __restrict__ beta,
        int base, int cnt, float* cA, float* cB) {
    int t = threadIdx.x;
    if (t < cnt) {
        int ch = base + t;
        float s = STATS[ch * 2] + STATS[256 + ch * 2] + STATS[512 + ch * 2] + STATS[768 + ch * 2];
        float q = STATS[ch * 2 + 1] + STATS[256 + ch * 2 + 1] + STATS[512 + ch * 2 + 1] + STATS[768 + ch * 2 + 1];
        float mu = s * INVN;
        float var = q * INVN - mu * mu;
        float A = g[t] * rsqrtf(var + BN_EPS);
        cA[t] = A;
        cB[t] = beta[t] - mu * A;
    }
}

// ---- weight prep + stats zero + out b8-init ----
__global__ __launch_bounds__(256) void k_wprep(
        const float* __restrict__ W5a, const float* __restrict__ W5c,
        const float* __restrict__ W6, const float* __restrict__ W7,
        const float* __restrict__ W51, const float* __restrict__ W52,
        const float* __restrict__ Wq, const float* __restrict__ Wk,
        const float* __restrict__ Wv, const float* __restrict__ bq,
        const float* __restrict__ bk, const float* __restrict__ bv,
        const float* __restrict__ b8,
        unsigned short* __restrict__ W5BF, unsigned short* __restrict__ W67,
        unsigned short* __restrict__ WT, unsigned short* __restrict__ WQKV,
        float* __restrict__ BQKV, float* __restrict__ STATS1,
        float* __restrict__ STATS2, float* __restrict__ out_sasc) {
    int i = blockIdx.x * 256 + threadIdx.x;
    if (i < 32768) {
        int o = i >> 8, c = i & 255;
        W5BF[i] = f2bf(o < 64 ? W5a[o * 256 + c] : W5c[(o - 64) * 256 + c]);
    } else if (i < 49152) {
        int j = i - 32768; int g = j >> 13; int r = j & 8191;
        W67[j] = f2bf(g ? W7[r] : W6[r]);
    } else if (i < 73728) {
        int j = i - 49152;
        int c = j & 63, o = (j >> 6) & 63, wt = j >> 12; int w = wt / 3, t = wt % 3;
        const float* Ws = w ? W52 : W51;
        WT[j] = f2bf(Ws[(o * 64 + c) * 3 + t]);
    } else if (i < 78848) {
        int j = i - 73728; int o = j >> 6, c = j & 63;
        float v = o < 8 ? Wq[o * 64 + c] : (o < 16 ? Wk[(o - 8) * 64 + c] : Wv[(o - 16) * 64 + c]);
        WQKV[j] = f2bf(v);
    } else if (i < 78928) {
        int o = i - 78848;
        BQKV[o] = o < 8 ? bq[o] : (o < 16 ? bk[o - 8] : bv[o - 16]);
    } else if (i < 80976) {
        int j = i - 78928;
        if (j < 1024) STATS1[j] = 0.f; else STATS2[j - 1024] = 0.f;
    } else if (i < 82000) {
        int j = i - 80976;
        out_sasc[j] = b8[j & 127];
    }
}

// ---- conv1x1(x): single coalesced x pass; pre-BN bf16 + atomic stats ----
__global__ __launch_bounds__(256) void k_conv1(const float* __restrict__ x,
        const unsigned short* __restrict__ W5BF,
        unsigned short* __restrict__ Y1T, unsigned short* __restrict__ Y2C,
        float* __restrict__ STATS1) {
    __shared__ unsigned short xt[64][264];
    __shared__ float lds_part[4][64];
    int lt = blockIdx.x, b = blockIdx.y;
    int l0 = lt * 64;
    int t = threadIdx.x;
    {   // stage: lane j = l offset (coalesced), cg = channel quarter; packed b128 writes
        int j = t & 63, cg = t >> 6;
        int ls = l0 - 1 + j;
        bool ok = (ls >= 0) && (ls < L);
        const float* xs = x + (size_t)(b * C + cg * 64) * L + ls;
        unsigned short* row = &xt[j][cg * 64];
#pragma unroll
        for (int c8 = 0; c8 < 8; ++c8) {
            unsigned int pk[4];
#pragma unroll
            for (int i = 0; i < 4; ++i) {
                float v0 = ok ? xs[(size_t)(c8 * 8 + 2 * i) * L] : 0.f;
                float v1 = ok ? xs[(size_t)(c8 * 8 + 2 * i + 1) * L] : 0.f;
                pk[i] = pk2(v0, v1);
            }
            *(uint4*)(row + c8 * 8) = *(const uint4*)pk;
        }
    }
    __syncthreads();
    int w = t >> 6, lane = t & 63, n = lane & 15, quad = lane >> 4;
    bshort8 wf[2][8];
#pragma unroll
    for (int oi = 0; oi < 2; ++oi)
#pragma unroll
        for (int kt = 0; kt < 8; ++kt)
            wf[oi][kt] = *(const bshort8*)(W5BF + (size_t)((w * 2 + oi) * 16 + n) * C + kt * 32 + quad * 8);
    f32x4 acc[2][4];
#pragma unroll
    for (int oi = 0; oi < 2; ++oi)
#pragma unroll
        for (int sub = 0; sub < 4; ++sub) acc[oi][sub] = (f32x4){0.f, 0.f, 0.f, 0.f};
#pragma unroll
    for (int sub = 0; sub < 4; ++sub) {
        int lloc = sub * 16 + n;
#pragma unroll
        for (int kt = 0; kt < 8; ++kt) {
            bshort8 xb = *(const bshort8*)(&xt[lloc][kt * 32 + quad * 8]);
            acc[0][sub] = __builtin_amdgcn_mfma_f32_16x16x32_bf16(wf[0][kt], xb, acc[0][sub], 0, 0, 0);
            acc[1][sub] = __builtin_amdgcn_mfma_f32_16x16x32_bf16(wf[1][kt], xb, acc[1][sub], 0, 0, 0);
        }
    }
    if (w < 2) {
#pragma unroll
        for (int sub = 0; sub < 4; ++sub) {
            int lp = l0 + sub * 16 + n;
#pragma unroll
            for (int oi = 0; oi < 2; ++oi) {
                int ot = w * 2 + oi;
                uint2 pv;
                pv.x = pk2(acc[oi][sub][0], acc[oi][sub][1]);
                pv.y = pk2(acc[oi][sub][2], acc[oi][sub][3]);
                *(uint2*)(Y1T + ((size_t)(b * LP + lp)) * IC + ot * 16 + quad * 4) = pv;
            }
        }
    } else {
#pragma unroll
        for (int oi = 0; oi < 2; ++oi) {
            int ot = (w - 2) * 2 + oi;
#pragma unroll
            for (int r = 0; r < 4; ++r) {
                int o = ot * 16 + quad * 4 + r;
                unsigned short* dst = Y2C + ((size_t)(b * IC + o)) * LP + l0;
#pragma unroll
                for (int sub = 0; sub < 4; ++sub)
                    dst[sub * 16 + n] = f2bf(acc[oi][sub][r]);
            }
        }
    }
#pragma unroll
    for (int oi = 0; oi < 2; ++oi)
#pragma unroll
        for (int r = 0; r < 4; ++r) {
            float s = 0.f, q = 0.f;
#pragma unroll
            for (int sub = 0; sub < 4; ++sub) {
                float v = acc[oi][sub][r];
                s += v; q += v * v;
            }
#pragma unroll
            for (int msk = 1; msk < 16; msk <<= 1) {
                s += __shfl_xor(s, msk, 64);
                q += __shfl_xor(q, msk, 64);
            }
            if (n == 0) {
                int ci = oi * 16 + quad * 4 + r;
                lds_part[w][ci * 2] = s;
                lds_part[w][ci * 2 + 1] = q;
            }
        }
    __syncthreads();
    {
        int ch = t >> 1, wsrc = ch >> 5;
        int idx = ((ch & 31) << 1) | (t & 1);
        atomicAdd(&STATS1[(blockIdx.x & 3) * 256 + t], lds_part[wsrc][idx]);
    }
}

// ================= fuse1: qkv (256 blocks) | gram (32 blocks) =================
__device__ void role_qkv(char* dynsm, int lt, int b,
        const unsigned short* __restrict__ Y1T, const float* __restrict__ STATS1,
        const float* __restrict__ g5a, const float* __restrict__ b5a,
        const unsigned short* __restrict__ WQKV, const float* __restrict__ BQKV,
        unsigned short* __restrict__ QT, unsigned short* __restrict__ KT,
        unsigned short* __restrict__ VB) {
    float* cA = (float*)dynsm;
    float* cB = cA + 64;
    load_coef(STATS1, g5a, b5a, 0, 64, cA, cB);
    __syncthreads();
    int t = threadIdx.x;
    int w = t >> 6, lane = t & 63, n = lane & 15, quad = lane >> 4;
    int lrow = lt * 64 + w * 16 + n;
    bshort8 fb[2];
#pragma unroll
    for (int kt = 0; kt < 2; ++kt) {
        bshort8 raw = *(const bshort8*)(Y1T + ((size_t)(b * LP + lrow)) * IC + kt * 32 + quad * 8);
        bshort8 f;
#pragma unroll
        for (int j = 0; j < 8; ++j) {
            int c = kt * 32 + quad * 8 + j;
            float v = fmaxf(fmaf(cA[c], bf2f((unsigned short)raw[j]), cB[c]), 0.f);
            ((unsigned short*)&f)[j] = f2bf(v);
        }
        fb[kt] = f;
    }
    f32x4 acc[5];
#pragma unroll
    for (int ot = 0; ot < 5; ++ot) {
        f32x4 a = {0.f, 0.f, 0.f, 0.f};
#pragma unroll
        for (int kt = 0; kt < 2; ++kt) {
            bshort8 wf = *(const bshort8*)(WQKV + (size_t)(ot * 16 + n) * IC + kt * 32 + quad * 8);
            a = __builtin_amdgcn_mfma_f32_16x16x32_bf16(wf, fb[kt], a, 0, 0, 0);
        }
        acc[ot] = a;
    }
#pragma unroll
    for (int ot = 0; ot < 5; ++ot)
#pragma unroll
        for (int r = 0; r < 4; ++r) {
            int o = ot * 16 + quad * 4 + r;
            unsigned short bv16 = f2bf(acc[ot][r] + BQKV[o]);
            if (ot == 0) {
                if (o < 8) QT[((size_t)(b * LP + lrow)) * 8 + o] = bv16;
                else KT[((size_t)(b * LP + lrow)) * 8 + (o - 8)] = bv16;
            } else {
                VB[((size_t)(b * IC + (o - 16))) * LP + lrow] = bv16;
            }
        }
}

__device__ void role_gram(char* dynsm, int blk, int b,
        const unsigned short* __restrict__ Y2C, const float* __restrict__ STATS1,
        const float* __restrict__ g5c, const float* __restrict__ b5c,
        float* __restrict__ EPART) {
    float* cA = (float*)dynsm;
    float* cB = cA + 64;
    load_coef(STATS1, g5c, b5c, 64, 64, cA, cB);
    __syncthreads();
    int t = threadIdx.x;
    int w = t >> 6, lane = t & 63, n = lane & 15, quad = lane >> 4;
    f32x4 acc[4][4];
#pragma unroll
    for (int ti = 0; ti < 4; ++ti)
#pragma unroll
        for (int tj = 0; tj < 4; ++tj) acc[ti][tj] = (f32x4){0.f, 0.f, 0.f, 0.f};
    for (int chunk = 0; chunk < 4; ++chunk) {
        int lb = (blk * 4 + w) * 128 + chunk * 32 + quad * 8;
        bshort8 frag[4];
#pragma unroll
        for (int g = 0; g < 4; ++g) {
            int c = g * 16 + n;
            bshort8 raw = *(const bshort8*)(Y2C + ((size_t)(b * IC + c)) * LP + lb);
            bshort8 f;
            float A = cA[c], Bc = cB[c];
#pragma unroll
            for (int j = 0; j < 8; ++j)
                ((unsigned short*)&f)[j] = f2bf(fmaxf(fmaf(A, bf2f((unsigned short)raw[j]), Bc), 0.f));
            frag[g] = f;
        }
#pragma unroll
        for (int ti = 0; ti < 4; ++ti)
#pragma unroll
            for (int tj = 0; tj < 4; ++tj)
                acc[ti][tj] = __builtin_amdgcn_mfma_f32_16x16x32_bf16(frag[ti], frag[tj], acc[ti][tj], 0, 0, 0);
    }
    float* ep = EPART + ((size_t)(b * 16 + blk * 4 + w)) * 4096;
#pragma unroll
    for (int ti = 0; ti < 4; ++ti)
#pragma unroll
        for (int tj = 0; tj < 4; ++tj)
#pragma unroll
            for (int r = 0; r < 4; ++r)
                ep[(ti * 16 + quad * 4 + r) * 64 + tj * 16 + n] = acc[ti][tj][r];
}

__global__ __launch_bounds__(256) void k_fuse1(
        const unsigned short* __restrict__ Y1T, const unsigned short* __restrict__ Y2C,
        const float* __restrict__ STATS1,
        const float* __restrict__ g5a, const float* __restrict__ b5a,
        const float* __restrict__ g5c, const float* __restrict__ b5c,
        const unsigned short* __restrict__ WQKV, const float* __restrict__ BQKV,
        unsigned short* __restrict__ QT, unsigned short* __restrict__ KT,
        unsigned short* __restrict__ VB, float* __restrict__ EPART) {
    extern __shared__ char dynsm[];
    int idx = blockIdx.x;
    if (idx < 256) role_qkv(dynsm, idx & 31, idx >> 5, Y1T, STATS1, g5a, b5a,
                            WQKV, BQKV, QT, KT, VB);
    else { int g = idx - 256; role_gram(dynsm, g & 3, g >> 2, Y2C, STATS1, g5c, b5c, EPART); }
}

// ===== fuse2: pam (1024 blocks, V double-buffered) | cam_softmax (8) =====
__device__ void role_pam(char* dynsm, int qt, int ks, int b,
        const unsigned short* __restrict__ qT, const unsigned short* __restrict__ kT,
        const unsigned short* __restrict__ vb,
        unsigned short* __restrict__ OPART, float* __restrict__ LPART) {
    unsigned short* vs0 = (unsigned short*)dynsm;     // [64][72]
    unsigned short* vs1 = vs0 + 4608;                 // [64][72]
    unsigned short* ps  = vs1 + 4608;                 // 4 x [16][72]
    float* os = (float*)dynsm;                        // [64][65] aliased after loop
    int l0 = qt * 64;
    int tid = threadIdx.x;
    int wq = tid >> 6, lane = tid & 63, n = lane & 15, quad = lane >> 4;
    int srow = tid >> 2, schn = tid & 3;
    bshort8 qa = {};
    if (quad == 0)
        qa = *(const bshort8*)(qT + ((size_t)(b * LP + l0 + wq * 16 + n)) * 8);
    f32x4 acc[4];
#pragma unroll
    for (int s = 0; s < 4; ++s) acc[s] = (f32x4){0.f, 0.f, 0.f, 0.f};
    float li[4] = {0.f, 0.f, 0.f, 0.f};
    unsigned short* pw = ps + wq * 16 * 72;

    {   // prologue: stage tile 0
        const unsigned short* src = vb + ((size_t)(b * IC + srow)) * LP + ks * 512 + schn * 16;
        unsigned short* d = vs0 + srow * 72 + schn * 16;
        *(bshort8*)d = *(const bshort8*)src;
        *(bshort8*)(d + 8) = *(const bshort8*)(src + 8);
    }
    __syncthreads();
    for (int it = 0; it < 8; ++it) {
        unsigned short* cur = (it & 1) ? vs1 : vs0;
        unsigned short* nxt = (it & 1) ? vs0 : vs1;
        if (it < 7) {
            const unsigned short* src = vb + ((size_t)(b * IC + srow)) * LP + ks * 512 + (it + 1) * 64 + schn * 16;
            unsigned short* d = nxt + srow * 72 + schn * 16;
            *(bshort8*)d = *(const bshort8*)src;
            *(bshort8*)(d + 8) = *(const bshort8*)(src + 8);
        }
        int m0 = ks * 512 + it * 64;
        bshort8 kb[4];
#pragma unroll
        for (int s = 0; s < 4; ++s) kb[s] = (bshort8){};
        if (quad == 0) {
#pragma unroll
            for (int s = 0; s < 4; ++s)
                kb[s] = *(const bshort8*)(kT + ((size_t)(b * LP + m0 + s * 16 + n)) * 8);
        }
        f32x4 sc[4];
#pragma unroll
        for (int s = 0; s < 4; ++s)
            sc[s] = __builtin_amdgcn_mfma_f32_16x16x32_bf16(qa, kb[s],
                        (f32x4){0.f, 0.f, 0.f, 0.f}, 0, 0, 0);
#pragma unroll
        for (int s = 0; s < 4; ++s)
#pragma unroll
            for (int r = 0; r < 4; ++r) {
                float p = __expf(sc[s][r]);
                li[r] += p;
                pw[(quad * 4 + r) * 72 + s * 16 + n] = f2bf(p);
            }
#pragma unroll
        for (int step = 0; step < 2; ++step) {
            bshort8 pa = *(const bshort8*)(pw + n * 72 + step * 32 + quad * 8);
#pragma unroll
            for (int s = 0; s < 4; ++s) {
                bshort8 vf = *(const bshort8*)(cur + (s * 16 + n) * 72 + step * 32 + quad * 8);
                acc[s] = __builtin_amdgcn_mfma_f32_16x16x32_bf16(pa, vf, acc[s], 0, 0, 0);
            }
        }
        __syncthreads();
    }
#pragma unroll
    for (int s = 0; s < 4; ++s)
#pragma unroll
        for (int r = 0; r < 4; ++r)
            os[(s * 16 + n) * 65 + wq * 16 + quad * 4 + r] = acc[s][r];
    size_t lbase = ((size_t)((b * 32 + qt) * 4 + ks)) * 64;
#pragma unroll
    for (int r = 0; r < 4; ++r) {
        float s_ = li[r];
#pragma unroll
        for (int msk = 1; msk < 16; msk <<= 1) s_ += __shfl_xor(s_, msk, 64);
        if (n == 0) LPART[lbase + wq * 16 + quad * 4 + r] = s_;
    }
    __syncthreads();
    size_t ob = ((size_t)((b * 32 + qt) * 4 + ks)) * 4096;
    int c = tid >> 2, qc = tid & 3;
    unsigned int* od = (unsigned int*)(OPART + ob + c * 64 + qc * 16);
#pragma unroll
    for (int i = 0; i < 8; ++i)
        od[i] = pk2(os[c * 65 + qc * 16 + 2 * i], os[c * 65 + qc * 16 + 2 * i + 1]);
}

__device__ void role_cam_softmax(char* dynsm, int b,
        const float* __restrict__ EPART, float* __restrict__ attn) {
    float* e = (float*)dynsm;
    int t = threadIdx.x;
    for (int idx = t; idx < 4096; idx += 256) {
        float s = 0.f;
        for (int ch = 0; ch < 16; ++ch) s += EPART[((size_t)(b * 16 + ch)) * 4096 + idx];
        e[idx] = s;
    }
    __syncthreads();
    if (t < 64) {
        float mn = INFINITY;
        for (int d = 0; d < 64; ++d) mn = fminf(mn, e[t * 64 + d]);
        float s = 0.f;
        float* a = attn + (size_t)b * 4096 + t * 64;
        for (int d = 0; d < 64; ++d) { float p = __expf(mn - e[t * 64 + d]); a[d] = p; s += p; }
        float inv = 1.f / s;
        for (int d = 0; d < 64; ++d) a[d] *= inv;
    }
}

__global__ __launch_bounds__(256) void k_fuse2(
        const unsigned short* __restrict__ QT, const unsigned short* __restrict__ KT,
        const unsigned short* __restrict__ VB,
        unsigned short* __restrict__ OPART, float* __restrict__ LPART,
        const float* __restrict__ EPART, float* __restrict__ ATTN) {
    extern __shared__ char dynsm[];
    int idx = blockIdx.x;
    if (idx < 1024) role_pam(dynsm, idx & 31, (idx >> 5) & 3, idx >> 7, QT, KT, VB, OPART, LPART);
    else role_cam_softmax(dynsm, idx - 1024, EPART, ATTN);
}

// ====== fuse3c: {pam_combine|cam_apply} + conv3 from LDS tile (512 blocks) ======
__device__ __forceinline__ void conv3_from_tile(const unsigned short* tile,
        const unsigned short* __restrict__ WT, unsigned short* __restrict__ dst,
        int b, int l0, float* lds_part, float* __restrict__ STATS2,
        int og, int blockx) {
    int t = threadIdx.x;
    int w = t >> 6, lane = t & 63, n = lane & 15, quad = lane >> 4;
    int lrow = l0 + w * 16 + n;
    f32x4 acc[4];
#pragma unroll
    for (int ot = 0; ot < 4; ++ot) acc[ot] = (f32x4){0.f, 0.f, 0.f, 0.f};
#pragma unroll
    for (int t3 = 0; t3 < 3; ++t3) {
        int trow = w * 16 + n + t3;
        bshort8 fb0 = *(const bshort8*)(tile + trow * 72 + quad * 8);
        bshort8 fb1 = *(const bshort8*)(tile + trow * 72 + 32 + quad * 8);
#pragma unroll
        for (int ot = 0; ot < 4; ++ot) {
            bshort8 w0 = *(const bshort8*)(WT + ((size_t)(t3 * 64 + ot * 16 + n)) * IC + quad * 8);
            bshort8 w1 = *(const bshort8*)(WT + ((size_t)(t3 * 64 + ot * 16 + n)) * IC + 32 + quad * 8);
            acc[ot] = __builtin_amdgcn_mfma_f32_16x16x32_bf16(w0, fb0, acc[ot], 0, 0, 0);
            acc[ot] = __builtin_amdgcn_mfma_f32_16x16x32_bf16(w1, fb1, acc[ot], 0, 0, 0);
        }
    }
#pragma unroll
    for (int ot = 0; ot < 4; ++ot) {
        uint2 pv;
        pv.x = pk2(acc[ot][0], acc[ot][1]);
        pv.y = pk2(acc[ot][2], acc[ot][3]);
        *(uint2*)(dst + ((size_t)(b * LP + lrow)) * IC + ot * 16 + quad * 4) = pv;
    }
#pragma unroll
    for (int ot = 0; ot < 4; ++ot)
#pragma unroll
        for (int r = 0; r < 4; ++r) {
            float s = acc[ot][r], q = s * s;
#pragma unroll
            for (int msk = 1; msk < 16; msk <<= 1) {
                s += __shfl_xor(s, msk, 64);
                q += __shfl_xor(q, msk, 64);
            }
            if (n == 0) {
                int cch = ot * 16 + quad * 4 + r;
                lds_part[w * 128 + cch * 2] = s;
                lds_part[w * 128 + cch * 2 + 1] = q;
            }
        }
    __syncthreads();
    if (t < 128) {
        float s = lds_part[t] + lds_part[128 + t] + lds_part[256 + t] + lds_part[384 + t];
        atomicAdd(&STATS2[(blockx & 3) * 256 + og * 128 + t], s);
    }
}

__device__ void role_pam_c3(char* dynsm, int qt, int b,
        const unsigned short* __restrict__ OPART, const float* __restrict__ LPART,
        const unsigned short* __restrict__ Y1T, const float* __restrict__ STATS1,
        const float* __restrict__ g5a, const float* __restrict__ b5a,
        const float* __restrict__ gamma, const unsigned short* __restrict__ WT,
        unsigned short* __restrict__ Y51T, float* __restrict__ STATS2) {
    float* dn = (float*)dynsm;
    float* cA = dn + 64; float* cB = cA + 64;
    unsigned short* tile = (unsigned short*)(cB + 64); // [66][72]
    float* lds_part = (float*)(tile + 4752);           // 512 floats
    int l0 = qt * 64;
    int t = threadIdx.x;
    load_coef(STATS1, g5a, b5a, 0, 64, cA, cB);
    if (t < 64) {
        size_t lbase = ((size_t)((b * 32 + qt) * 4)) * 64;
        dn[t] = LPART[lbase + t] + LPART[lbase + 64 + t] +
                LPART[lbase + 128 + t] + LPART[lbase + 192 + t];
    }
    __syncthreads();
    float gm = gamma[0];
    {
        int c = t >> 2, qc = t & 3;
        float O[16];
#pragma unroll
        for (int i = 0; i < 16; ++i) O[i] = 0.f;
        size_t ob = ((size_t)((b * 32 + qt) * 4)) * 4096 + c * 64 + qc * 16;
#pragma unroll
        for (int s = 0; s < 4; ++s) {
            bshort8 p0 = *(const bshort8*)(OPART + ob + (size_t)s * 4096);
            bshort8 p1 = *(const bshort8*)(OPART + ob + (size_t)s * 4096 + 8);
#pragma unroll
            for (int i = 0; i < 8; ++i) {
                O[i]     += bf2f((unsigned short)p0[i]);
                O[8 + i] += bf2f((unsigned short)p1[i]);
            }
        }
#pragma unroll
        for (int i = 0; i < 16; ++i) {
            int q = qc * 16 + i;
            unsigned short raw = Y1T[((size_t)(b * LP + l0 + q)) * IC + c];
            float f1v = fmaxf(fmaf(cA[c], bf2f(raw), cB[c]), 0.f);
            tile[(1 + q) * 72 + c] = f2bf(fmaf(gm, O[i] / dn[q], f1v));
        }
    }
    if (t < 128) {   // halo rows
        int row = (t & 1) ? 65 : 0;
        int ch = t >> 1;
        int l = l0 - 1 + row;
        float val = 0.f;
        if (l >= 0 && l < LP) {
            int qh = l >> 6, lih = l & 63;
            size_t lb2 = ((size_t)((b * 32 + qh) * 4)) * 64;
            float dnh = LPART[lb2 + lih] + LPART[lb2 + 64 + lih] +
                        LPART[lb2 + 128 + lih] + LPART[lb2 + 192 + lih];
            size_t ob2 = ((size_t)((b * 32 + qh) * 4)) * 4096 + ch * 64 + lih;
            float Oh = bf2f(OPART[ob2]) + bf2f(OPART[ob2 + 4096]) +
                       bf2f(OPART[ob2 + 8192]) + bf2f(OPART[ob2 + 12288]);
            float f1v = fmaxf(fmaf(cA[ch], bf2f(Y1T[((size_t)(b * LP + l)) * IC + ch]), cB[ch]), 0.f);
            val = fmaf(gm, Oh / dnh, f1v);
        }
        tile[row * 72 + ch] = f2bf(val);
    }
    __syncthreads();
    conv3_from_tile(tile, WT, Y51T, b, l0, lds_part, STATS2, 0, qt);
}

__device__ void role_cam_c3(char* dynsm, int lt, int b,
        const float* __restrict__ attn, const unsigned short* __restrict__ Y2C,
        const float* __restrict__ STATS1,
        const float* __restrict__ g5c, const float* __restrict__ b5c,
        const float* __restrict__ gamma, const unsigned short* __restrict__ WT,
        unsigned short* __restrict__ Y52T, float* __restrict__ STATS2) {
    float* as = (float*)dynsm;                         // 4096
    float* cA = as + 4096; float* cB = cA + 64;
    unsigned short* tile = (unsigned short*)(cB + 64); // [66][72]
    float* lds_part = (float*)(tile + 4752);           // 512 floats (also fcol scratch)
    int l0 = lt * 64;
    int t = threadIdx.x;
    load_coef(STATS1, g5c, b5c, 64, 64, cA, cB);
    for (int i = t; i < 4096; i += 256) as[i] = attn[(size_t)b * 4096 + i];
    __syncthreads();
    float gm = gamma[0];
    {   // interior: lq row, cg = 16-channel group
        int lq = t & 63, cg = t >> 6;
        const unsigned short* fb = Y2C + (size_t)b * IC * LP + l0 + lq;
        float acc[16];
#pragma unroll
        for (int i = 0; i < 16; ++i) acc[i] = 0.f;
        for (int d4 = 0; d4 < 16; ++d4) {
            float fv[4];
#pragma unroll
            for (int i = 0; i < 4; ++i) {
                int d = 4 * d4 + i;
                fv[i] = fmaxf(fmaf(cA[d], bf2f(fb[(size_t)d * LP]), cB[d]), 0.f);
            }
#pragma unroll
            for (int cc = 0; cc < 16; ++cc) {
                const float4 a4 = *reinterpret_cast<const float4*>(as + (cg * 16 + cc) * 64 + d4 * 4);
                acc[cc] += a4.x * fv[0] + a4.y * fv[1] + a4.z * fv[2] + a4.w * fv[3];
            }
        }
#pragma unroll
        for (int cc = 0; cc < 16; ++cc) {
            int c = cg * 16 + cc;
            float res = fmaxf(fmaf(cA[c], bf2f(fb[(size_t)c * LP]), cB[c]), 0.f);
            tile[(1 + lq) * 72 + c] = f2bf(fmaf(gm, acc[cc], res));
        }
    }
    // halo: stage the two BN'd f-columns to LDS once (64x fewer scattered loads)
    float* fcol = lds_part;   // 128 floats scratch (overwritten later by conv3 tail)
    if (t < 128) {
        int row = t >> 6;     // 0 -> l0-1, 1 -> l0+64
        int ch = t & 63;
        int l = l0 - 1 + row * 65;
        float v = 0.f;
        if (l >= 0 && l < LP)
            v = fmaxf(fmaf(cA[ch], bf2f(Y2C[(size_t)b * IC * LP + (size_t)ch * LP + l]), cB[ch]), 0.f);
        fcol[row * 64 + ch] = v;
    }
    __syncthreads();
    if (t < 128) {
        int sel = t & 1;          // 0 -> row 0 (l0-1), 1 -> row 65 (l0+64)
        int row = sel ? 65 : 0;
        int ch = t >> 1;
        int l = l0 - 1 + (sel ? 65 : 0);
        float val = 0.f;
        if (l >= 0 && l < LP) {
            const float* fc = fcol + sel * 64;
            float a = 0.f;
#pragma unroll 8
            for (int d = 0; d < 64; ++d) a = fmaf(as[ch * 64 + d], fc[d], a);
            val = fmaf(gm, a, fc[ch]);
        }
        tile[row * 72 + ch] = f2bf(val);
    }
    __syncthreads();
    conv3_from_tile(tile, WT, Y52T, b, l0, lds_part, STATS2, 1, lt);
}

__global__ __launch_bounds__(256) void k_fuse3c(
        const unsigned short* __restrict__ OPART, const float* __restrict__ LPART,
        const unsigned short* __restrict__ Y1T, const unsigned short* __restrict__ Y2C,
        const float* __restrict__ STATS1,
        const float* __restrict__ g5a, const float* __restrict__ b5a,
        const float* __restrict__ g5c, const float* __restrict__ b5c,
        const float* __restrict__ gpam, const float* __restrict__ gcam,
        const float* __restrict__ ATTN, const unsigned short* __restrict__ WTall,
        unsigned short* __restrict__ Y51T, unsigned short* __restrict__ Y52T,
        float* __restrict__ STATS2) {
    extern __shared__ char dynsm[];
    int idx = blockIdx.x;
    if (idx < 256) role_pam_c3(dynsm, idx & 31, idx >> 5, OPART, LPART, Y1T,
                               STATS1, g5a, b5a, gpam, WTall, Y51T, STATS2);
    else { int g = idx - 256; role_cam_c3(dynsm, g & 31, g >> 5, ATTN, Y2C,
                                          STATS1, g5c, b5c, gcam, WTall + 12288,
                                          Y52T, STATS2); }
}

// ---- final conv1x1 pair + fused sasc projection (out pre-initialized to b8) ----
__global__ __launch_bounds__(256) void k_final(const unsigned short* __restrict__ Y51T,
        const unsigned short* __restrict__ Y52T, const float* __restrict__ STATS2,
        const float* __restrict__ g51, const float* __restrict__ b51,
        const float* __restrict__ g52, const float* __restrict__ b52,
        const unsigned short* __restrict__ W67,
        const float* __restrict__ b6, const float* __restrict__ b7,
        const float* __restrict__ W8,
        float* __restrict__ out_sa, float* __restrict__ out_sc,
        float* __restrict__ out_sasc) {
    __shared__ float cA[128], cB[128];
    __shared__ float fsw[4][64];
    __shared__ float chsum[64];
    int lt = blockIdx.x, og = blockIdx.y, b = blockIdx.z;
    int t = threadIdx.x;
    if (t < 128) {
        float s = STATS2[t * 2] + STATS2[256 + t * 2] + STATS2[512 + t * 2] + STATS2[768 + t * 2];
        float q = STATS2[t * 2 + 1] + STATS2[256 + t * 2 + 1] + STATS2[512 + t * 2 + 1] + STATS2[768 + t * 2 + 1];
        float mu = s * INVN, var = q * INVN - mu * mu;
        float gv = t < 64 ? g51[t] : g52[t - 64];
        float bv = t < 64 ? b51[t] : b52[t - 64];
        float A = gv * rsqrtf(var + BN_EPS);
        cA[t] = A; cB[t] = bv - mu * A;
    }
    __syncthreads();
    int w = t >> 6, lane = t & 63, n = lane & 15, quad = lane >> 4;
    int lrow = lt * 64 + w * 16 + n;
    float fs_lane[16];
    bshort8 ba[2], bb[2];
#pragma unroll
    for (int kt = 0; kt < 2; ++kt) {
        bshort8 ra = *(const bshort8*)(Y51T + ((size_t)(b * LP + lrow)) * IC + kt * 32 + quad * 8);
        bshort8 rb = *(const bshort8*)(Y52T + ((size_t)(b * LP + lrow)) * IC + kt * 32 + quad * 8);
        bshort8 fa, fb;
#pragma unroll
        for (int j = 0; j < 8; ++j) {
            int c = kt * 32 + quad * 8 + j;
            float v1 = fmaxf(fmaf(cA[c], bf2f((unsigned short)ra[j]), cB[c]), 0.f);
            float v2 = fmaxf(fmaf(cA[64 + c], bf2f((unsigned short)rb[j]), cB[64 + c]), 0.f);
            ((unsigned short*)&fa)[j] = f2bf(v1);
            ((unsigned short*)&fb)[j] = f2bf(v2);
            fs_lane[kt * 8 + j] = v1 + v2;
        }
        ba[kt] = fa; bb[kt] = fb;
    }
    f32x4 accA[4], accB[4];
#pragma unroll
    for (int ot = 0; ot < 4; ++ot) {
        accA[ot] = (f32x4){0.f, 0.f, 0.f, 0.f};
        accB[ot] = (f32x4){0.f, 0.f, 0.f, 0.f};
    }
#pragma unroll
    for (int ot = 0; ot < 4; ++ot)
#pragma unroll
        for (int kt = 0; kt < 2; ++kt) {
            bshort8 wa = *(const bshort8*)(W67 + (size_t)(og * 64 + ot * 16 + n) * IC + kt * 32 + quad * 8);
            bshort8 wb = *(const bshort8*)(W67 + 8192 + (size_t)(og * 64 + ot * 16 + n) * IC + kt * 32 + quad * 8);
            accA[ot] = __builtin_amdgcn_mfma_f32_16x16x32_bf16(wa, ba[kt], accA[ot], 0, 0, 0);
            accB[ot] = __builtin_amdgcn_mfma_f32_16x16x32_bf16(wb, bb[kt], accB[ot], 0, 0, 0);
        }
#pragma unroll
    for (int ot = 0; ot < 4; ++ot)
#pragma unroll
        for (int r = 0; r < 4; ++r) {
            int o = og * 64 + ot * 16 + quad * 4 + r;
            out_sa[((size_t)(b * OC + o)) * LP + lrow] = accA[ot][r] + b6[o];
            out_sc[((size_t)(b * OC + o)) * LP + lrow] = accB[ot][r] + b7[o];
        }
    if (og == 0) {
#pragma unroll
        for (int i = 0; i < 16; ++i) {
            float s = fs_lane[i];
#pragma unroll
            for (int msk = 1; msk < 16; msk <<= 1) s += __shfl_xor(s, msk, 64);
            if (n == 0) {
                int c = (i >> 3) * 32 + quad * 8 + (i & 7);
                fsw[w][c] = s;
            }
        }
        __syncthreads();
        if (t < 64) chsum[t] = fsw[0][t] + fsw[1][t] + fsw[2][t] + fsw[3][t];
        __syncthreads();
        if (t < 128) {
            float s = 0.f;
            for (int c = 0; c < 64; ++c) s = fmaf(W8[t * 64 + c], chsum[c], s);
            atomicAdd(&out_sasc[b * OC + t], s * (1.f / (float)LP));
        }
    }
}

extern "C" void kernel_launch(void* const* d_in, const int* in_sizes, int n_in,
                              void* d_out, int out_size, void* d_ws, size_t ws_size,
                              hipStream_t stream) {
    (void)in_sizes; (void)n_in; (void)out_size; (void)ws_size;
    const float* x    = (const float*)d_in[0];
    const float* W5a  = (const float*)d_in[1];
    const float* g5a  = (const float*)d_in[2];
    const float* b5a  = (const float*)d_in[3];
    const float* W5c  = (const float*)d_in[4];
    const float* g5c  = (const float*)d_in[5];
    const float* b5c  = (const float*)d_in[6];
    const float* Wq   = (const float*)d_in[7];
    const float* bq   = (const float*)d_in[8];
    const float* Wk   = (const float*)d_in[9];
    const float* bk   = (const float*)d_in[10];
    const float* Wv   = (const float*)d_in[11];
    const float* bv   = (const float*)d_in[12];
    const float* gpam = (const float*)d_in[13];
    const float* gcam = (const float*)d_in[14];
    const float* W51  = (const float*)d_in[15];
    const float* g51  = (const float*)d_in[16];
    const float* b51  = (const float*)d_in[17];
    const float* W52  = (const float*)d_in[18];
    const float* g52  = (const float*)d_in[19];
    const float* b52  = (const float*)d_in[20];
    const float* W6   = (const float*)d_in[21];
    const float* b6   = (const float*)d_in[22];
    const float* W7   = (const float*)d_in[23];
    const float* b7   = (const float*)d_in[24];
    const float* W8   = (const float*)d_in[25];
    const float* b8   = (const float*)d_in[26];

    float* ws = (float*)d_ws;
    float* out = (float*)d_out;
    unsigned short* Y1T  = (unsigned short*)(ws + OFF_Y1T);
    unsigned short* Y2C  = (unsigned short*)(ws + OFF_Y2C);
    unsigned short* Y51T = (unsigned short*)(ws + OFF_Y51T);
    unsigned short* Y52T = (unsigned short*)(ws + OFF_Y52T);
    unsigned short* VB   = (unsigned short*)(ws + OFF_VB);
    unsigned short* QT   = (unsigned short*)(ws + OFF_QT);
    unsigned short* KT   = (unsigned short*)(ws + OFF_KT);
    float* LPART  = ws + OFF_LPART;
    float* EPART  = ws + OFF_EPART;
    float* ATTN   = ws + OFF_ATTN;
    float* STATS1 = ws + OFF_STATS1;
    float* STATS2 = ws + OFF_STATS2;
    unsigned short* W5BF = (unsigned short*)(ws + OFF_W5BF);
    unsigned short* W67  = (unsigned short*)(ws + OFF_W67);
    unsigned short* WT   = (unsigned short*)(ws + OFF_WT);
    unsigned short* WQKV = (unsigned short*)(ws + OFF_WQKV);
    float* BQKV = ws + OFF_BQKV;

    float* out_sa = out + B * OC;
    float* out_sc = out + B * OC + (size_t)B * OC * LP;
    unsigned short* OPART = (unsigned short*)out_sa;  // scratch, overwritten by k_final

    k_wprep<<<321, 256, 0, stream>>>(W5a, W5c, W6, W7, W51, W52, Wq, Wk, Wv,
                                     bq, bk, bv, b8, W5BF, W67, WT, WQKV, BQKV,
                                     STATS1, STATS2, out);
    k_conv1<<<dim3(32, B), 256, 0, stream>>>(x, W5BF, Y1T, Y2C, STATS1);
    k_fuse1<<<288, 256, 512, stream>>>(Y1T, Y2C, STATS1, g5a, b5a, g5c, b5c,
                                       WQKV, BQKV, QT, KT, VB, EPART);
    k_fuse2<<<1032, 256, 27648, stream>>>(QT, KT, VB, OPART, LPART, EPART, ATTN);
    k_fuse3c<<<512, 256, 28448, stream>>>(OPART, LPART, Y1T, Y2C, STATS1,
                                          g5a, b5a, g5c, b5c, gpam, gcam, ATTN,
                                          WT, Y51T, Y52T, STATS2);
    k_final<<<dim3(32, 2, B), 256, 0, stream>>>(Y51T, Y52T, STATS2, g51, b51, g52, b52,
                                                W67, b6, b7, W8, out_sa, out_sc, out);
}